// Round 10
// baseline (283.378 us; speedup 1.0000x reference)
//
#include <hip/hip_runtime.h>
#include <cstdint>

#define NHEAD 12
#define TLEN 2048
#define CDIM 768
#define NSETS 1023   // 512+256+128+64+32+16+8+4+2+1

typedef __attribute__((ext_vector_type(8))) _Float16 half8;
typedef __attribute__((ext_vector_type(2))) __fp16 fp16x2;
typedef __attribute__((ext_vector_type(8))) short short8;   // 8 bf16
typedef __attribute__((ext_vector_type(4))) float f32x4;

__device__ __forceinline__ float elu1(float x) { return x > 0.f ? x + 1.f : __expf(x); }

__device__ __forceinline__ unsigned pack2_bf16_trunc(float a, float b) {
    unsigned ua = __float_as_uint(a), ub = __float_as_uint(b);
    return __builtin_amdgcn_perm(ub, ua, 0x07060302);
}
__device__ __forceinline__ unsigned pack2_bf16_rne(float a, float b) {
    unsigned ua = __float_as_uint(a), ub = __float_as_uint(b);
    ua = ua + 0x7fff + ((ua >> 16) & 1);
    ub = ub + 0x7fff + ((ub >> 16) & 1);
    return (ub & 0xffff0000u) | (ua >> 16);
}
__device__ __forceinline__ short8 mk_short8(const unsigned* u) {
    union { unsigned w[4]; short8 s; } x;
    x.w[0] = u[0]; x.w[1] = u[1]; x.w[2] = u[2]; x.w[3] = u[3];
    return x.s;
}
__device__ __forceinline__ void split8_bf16(const float* f, short8& hi, short8& lo) {
    unsigned hp[4], lp[4];
    #pragma unroll
    for (int p = 0; p < 4; ++p) {
        float a = f[2 * p], b = f[2 * p + 1];
        unsigned ua = __float_as_uint(a), ub = __float_as_uint(b);
        hp[p] = __builtin_amdgcn_perm(ub, ua, 0x07060302);
        float ra = a - __uint_as_float(ua & 0xffff0000u);
        float rb = b - __uint_as_float(ub & 0xffff0000u);
        lp[p] = pack2_bf16_trunc(ra, rb);
    }
    hi = mk_short8(hp); lo = mk_short8(lp);
}
__device__ __forceinline__ void split8_f16(const float* f, half8& hi, half8& lo) {
    union { fp16x2 h2[4]; half8 h8; } uh, ul;
    #pragma unroll
    for (int jp = 0; jp < 4; ++jp) {
        float a = f[2 * jp], b = f[2 * jp + 1];
        fp16x2 hh = __builtin_amdgcn_cvt_pkrtz(a, b);
        uh.h2[jp] = hh;
        ul.h2[jp] = __builtin_amdgcn_cvt_pkrtz(a - (float)hh[0], b - (float)hh[1]);
    }
    hi = uh.h8; lo = ul.h8;
}

// ---------- prep: 768x768 W -> f16 fragment-major blob ----------
__global__ __launch_bounds__(256) void prep_w768(
    const float* __restrict__ W, _Float16* __restrict__ blob)
{
    const int idx = blockIdx.x * 256 + threadIdx.x;
    const int k = idx / 768, n = idx % 768;
    const int i = k >> 5, kl = k & 31;
    const int quad = kl >> 3, j = kl & 7;
    const int nsg = n >> 4, lane15 = n & 15;
    const int lane = quad * 16 + lane15;
    blob[((size_t)(i * 48 + nsg) * 64 + lane) * 8 + j] = (_Float16)W[idx];
}

// fused Q/K/V prep
__global__ __launch_bounds__(256) void prep_w768x3(
    const float* __restrict__ Wq, const float* __restrict__ Wk,
    const float* __restrict__ Wv, _Float16* __restrict__ blobs)
{
    const int g = blockIdx.x;          // 3*2304
    const int sel = g / 2304;
    const float* W = sel == 0 ? Wq : (sel == 1 ? Wk : Wv);
    _Float16* blob = blobs + (size_t)sel * 589824;
    const int idx = (g % 2304) * 256 + threadIdx.x;
    const int k = idx / 768, n = idx % 768;
    const int i = k >> 5, kl = k & 31;
    const int quad = kl >> 3, j = kl & 7;
    const int nsg = n >> 4, lane15 = n & 15;
    const int lane = quad * 16 + lane15;
    blob[((size_t)(i * 48 + nsg) * 64 + lane) * 8 + j] = (_Float16)W[idx];
}

// ---------- MFMA GEMM core (final projection) ----------
template<int ACT, int BIAS>
__global__ __launch_bounds__(256, 3) void gemm_mfma(
    const float* __restrict__ A, const _Float16* __restrict__ Bblob,
    const float* __restrict__ bias, float* __restrict__ Cmat,
    int M, int N, int K)
{
    __shared__ float As[2][32][68];
    const int tid = threadIdx.x;
    const int wave = tid >> 6, lane = tid & 63;
    const int lane15 = lane & 15, quad = lane >> 4;
    const int m0 = blockIdx.y * 32;
    const int nsgBase = blockIdx.x * 4 + wave;
    const int nchunks = K >> 6;

    const half8* __restrict__ Bc = (const half8*)Bblob;

    #pragma unroll
    for (int u = 0; u < 2; ++u) {
        int c = tid + u * 256;
        int row = c >> 4, col = (c & 15) * 4;
        *(float4*)&As[0][row][col] = *(const float4*)&A[(size_t)(m0 + row) * K + col];
    }
    __syncthreads();

    f32x4 acc[2];
    acc[0] = (f32x4){0.f, 0.f, 0.f, 0.f};
    acc[1] = (f32x4){0.f, 0.f, 0.f, 0.f};

    for (int ch = 0; ch < nchunks; ++ch) {
        const int buf = ch & 1;
        float4 pre[2];
        if (ch + 1 < nchunks) {
            #pragma unroll
            for (int u = 0; u < 2; ++u) {
                int c = tid + u * 256;
                int row = c >> 4, col = (c & 15) * 4;
                pre[u] = *(const float4*)&A[(size_t)(m0 + row) * K + (ch + 1) * 64 + col];
            }
        }
        #pragma unroll
        for (int kt = 0; kt < 2; ++kt) {
            half8 bb = Bc[(size_t)((ch * 2 + kt) * 48 + nsgBase) * 64 + lane];
            #pragma unroll
            for (int ms = 0; ms < 2; ++ms) {
                float f[8];
                *(float4*)&f[0] = *(const float4*)&As[buf][ms * 16 + lane15][kt * 32 + quad * 8];
                *(float4*)&f[4] = *(const float4*)&As[buf][ms * 16 + lane15][kt * 32 + quad * 8 + 4];
                half8 ah, al;
                split8_f16(f, ah, al);
                acc[ms] = __builtin_amdgcn_mfma_f32_16x16x32_f16(ah, bb, acc[ms], 0, 0, 0);
                acc[ms] = __builtin_amdgcn_mfma_f32_16x16x32_f16(al, bb, acc[ms], 0, 0, 0);
            }
        }
        if (ch + 1 < nchunks) {
            #pragma unroll
            for (int u = 0; u < 2; ++u) {
                int c = tid + u * 256;
                int row = c >> 4, col = (c & 15) * 4;
                *(float4*)&As[1 - buf][row][col] = pre[u];
            }
        }
        __syncthreads();
    }

    const int coln = blockIdx.x * 64 + wave * 16 + lane15;
    #pragma unroll
    for (int ms = 0; ms < 2; ++ms)
        #pragma unroll
        for (int r = 0; r < 4; ++r) {
            int row = m0 + ms * 16 + quad * 4 + r;
            float v = acc[ms][r];
            if (BIAS) v += bias[coln];
            if (ACT) v = elu1(v);
            Cmat[(size_t)row * N + coln] = v;
        }
}

// ---------- fused QKV projection ----------
__global__ __launch_bounds__(256, 3) void gemm_qkv(
    const float* __restrict__ A, const _Float16* __restrict__ blobs,
    float* __restrict__ outbase)
{
    __shared__ float As[2][32][68];
    const int which = blockIdx.x / 12;
    const int bx = blockIdx.x % 12;
    const _Float16* Bblob = blobs + (size_t)which * 589824;
    float* Cmat = outbase + (size_t)which * ((size_t)TLEN * CDIM);
    const bool act = which < 2;

    const int tid = threadIdx.x;
    const int wave = tid >> 6, lane = tid & 63;
    const int lane15 = lane & 15, quad = lane >> 4;
    const int m0 = blockIdx.y * 32;
    const int nsgBase = bx * 4 + wave;
    const int nchunks = CDIM >> 6;   // 12

    const half8* __restrict__ Bc = (const half8*)Bblob;

    #pragma unroll
    for (int u = 0; u < 2; ++u) {
        int c = tid + u * 256;
        int row = c >> 4, col = (c & 15) * 4;
        *(float4*)&As[0][row][col] = *(const float4*)&A[(size_t)(m0 + row) * CDIM + col];
    }
    __syncthreads();

    f32x4 acc[2];
    acc[0] = (f32x4){0.f, 0.f, 0.f, 0.f};
    acc[1] = (f32x4){0.f, 0.f, 0.f, 0.f};

    for (int ch = 0; ch < nchunks; ++ch) {
        const int buf = ch & 1;
        float4 pre[2];
        if (ch + 1 < nchunks) {
            #pragma unroll
            for (int u = 0; u < 2; ++u) {
                int c = tid + u * 256;
                int row = c >> 4, col = (c & 15) * 4;
                pre[u] = *(const float4*)&A[(size_t)(m0 + row) * CDIM + (ch + 1) * 64 + col];
            }
        }
        #pragma unroll
        for (int kt = 0; kt < 2; ++kt) {
            half8 bb = Bc[(size_t)((ch * 2 + kt) * 48 + nsgBase) * 64 + lane];
            #pragma unroll
            for (int ms = 0; ms < 2; ++ms) {
                float f[8];
                *(float4*)&f[0] = *(const float4*)&As[buf][ms * 16 + lane15][kt * 32 + quad * 8];
                *(float4*)&f[4] = *(const float4*)&As[buf][ms * 16 + lane15][kt * 32 + quad * 8 + 4];
                half8 ah, al;
                split8_f16(f, ah, al);
                acc[ms] = __builtin_amdgcn_mfma_f32_16x16x32_f16(ah, bb, acc[ms], 0, 0, 0);
                acc[ms] = __builtin_amdgcn_mfma_f32_16x16x32_f16(al, bb, acc[ms], 0, 0, 0);
            }
        }
        if (ch + 1 < nchunks) {
            #pragma unroll
            for (int u = 0; u < 2; ++u) {
                int c = tid + u * 256;
                int row = c >> 4, col = (c & 15) * 4;
                *(float4*)&As[1 - buf][row][col] = pre[u];
            }
        }
        __syncthreads();
    }

    const int coln = bx * 64 + wave * 16 + lane15;
    #pragma unroll
    for (int ms = 0; ms < 2; ++ms)
        #pragma unroll
        for (int r = 0; r < 4; ++r) {
            int row = m0 + ms * 16 + quad * 4 + r;
            float v = acc[ms][r];
            if (act) v = elu1(v);
            Cmat[(size_t)row * CDIM + coln] = v;
        }
}

// ---------- prep: map W -> f16 fragment-major blob (4096x128) ----------
__global__ __launch_bounds__(256) void prep_w(
    const float* __restrict__ Wks, const float* __restrict__ Wvs,
    _Float16* __restrict__ Wblob)
{
    const int idx = blockIdx.x * 256 + threadIdx.x;
    const int kk = idx >> 7, n = idx & 127;
    float f = (n < 64) ? Wks[(size_t)kk * 64 + n] : Wvs[(size_t)kk * 64 + (n - 64)];
    const int i = kk >> 6, kl = kk & 63;
    const int ks = kl >> 5, quad = (kl >> 3) & 3, j = kl & 7;
    const int nsg = n >> 4, lane15 = n & 15;
    const int lane = quad * 16 + lane15;
    const size_t off = ((size_t)(((i * 2 + ks) * 8 + nsg)) * 64 + lane) * 8 + j;
    Wblob[off] = (_Float16)f;
}

// ---------- MFMA mapped features v3: 4-stage software-pipelined B/K prefetch ----------
__global__ __launch_bounds__(256, 3) void map_f16(
    const float* __restrict__ kbuf, const float* __restrict__ vbuf,
    const _Float16* __restrict__ Wblob,
    float* __restrict__ kkv, float* __restrict__ vvv)
{
    __shared__ float kS[32][68];

    const int tid = threadIdx.x;
    const int p0 = blockIdx.x * 32;
    const int wave = tid >> 6, lane = tid & 63;
    const int lane15 = lane & 15, quad = lane >> 4;
    const int mh = wave & 1;    // position half
    const int nh = wave >> 1;   // output half: 0 -> kkv cols, 1 -> vvv cols

    #pragma unroll
    for (int u = 0; u < 2; ++u) {
        int c = tid + u * 256;
        int row = c >> 4, col = (c & 15) * 4;
        *(float4*)&kS[row][col] = *(const float4*)&kbuf[(size_t)(p0 + row) * 64 + col];
    }

    float vr[2][8];
    {
        const size_t pbase = (size_t)(p0 + mh * 16 + lane15) * 64;
        #pragma unroll
        for (int ks = 0; ks < 2; ++ks) {
            *(float4*)&vr[ks][0] = *(const float4*)&vbuf[pbase + ks * 32 + quad * 8];
            *(float4*)&vr[ks][4] = *(const float4*)&vbuf[pbase + ks * 32 + quad * 8 + 4];
        }
    }
    __syncthreads();

    const half8* __restrict__ Wc = (const half8*)Wblob;

    f32x4 acc[4];
    #pragma unroll
    for (int nsl = 0; nsl < 4; ++nsl) acc[nsl] = (f32x4){0.f, 0.f, 0.f, 0.f};

    half8 b0[4], b1[4], b2[4], b3[4];
    float k0, k1, k2, k3;

    auto loadB = [&](half8* b, int s) {
        #pragma unroll
        for (int nsl = 0; nsl < 4; ++nsl)
            b[nsl] = Wc[(size_t)(s * 8 + nh * 4 + nsl) * 64 + lane];
    };
    auto loadK = [&](float& kf, int s) { kf = kS[mh * 16 + lane15][s >> 1]; };
    auto compute = [&](const half8* b, float kf, int s) {
        const int ks = s & 1;
        float f[8];
        #pragma unroll
        for (int j = 0; j < 8; ++j) f[j] = kf * vr[ks][j];
        half8 ah, al;
        split8_f16(f, ah, al);
        #pragma unroll
        for (int nsl = 0; nsl < 4; ++nsl)
            acc[nsl] = __builtin_amdgcn_mfma_f32_16x16x32_f16(ah, b[nsl], acc[nsl], 0, 0, 0);
        #pragma unroll
        for (int nsl = 0; nsl < 4; ++nsl)
            acc[nsl] = __builtin_amdgcn_mfma_f32_16x16x32_f16(al, b[nsl], acc[nsl], 0, 0, 0);
    };

    loadB(b0, 0); loadB(b1, 1); loadB(b2, 2); loadB(b3, 3);
    loadK(k0, 0); loadK(k1, 1); loadK(k2, 2); loadK(k3, 3);
    for (int s = 0; s < 128; s += 4) {
        const bool more = (s + 4) < 128;
        compute(b0, k0, s);
        compute(b1, k1, s + 1);
        if (more) { loadB(b0, s + 4); loadK(k0, s + 4); loadB(b1, s + 5); loadK(k1, s + 5); }
        compute(b2, k2, s + 2);
        compute(b3, k3, s + 3);
        if (more) { loadB(b2, s + 6); loadK(k2, s + 6); loadB(b3, s + 7); loadK(k3, s + 7); }
    }

    // epilogue: C/D layout col=lane15, row=quad*4+r
    float* dst = nh ? vvv : kkv;
    #pragma unroll
    for (int nsl = 0; nsl < 4; ++nsl)
        #pragma unroll
        for (int r = 0; r < 4; ++r) {
            int p = p0 + mh * 16 + quad * 4 + r;
            int col = nsl * 16 + lane15;
            dst[(size_t)p * 64 + col] = acc[nsl][r];
        }
}

// ---------- set features (levels 2..7) + fused tail cumsum ----------
__global__ __launch_bounds__(256) void set_lower(
    const float* __restrict__ kkv, const float* __restrict__ vvv,
    const float* __restrict__ bks, const float* __restrict__ bvs,
    float* __restrict__ Kset, float* __restrict__ Vset,
    float* __restrict__ scrK, float* __restrict__ scrV,
    float* __restrict__ Kt, float* __restrict__ Vt)
{
    __shared__ float curK[63][64];
    __shared__ float curV[63][64];
    const int tid = threadIdx.x;
    const int col = tid & 63, grp = tid >> 6;
    const int h = blockIdx.x % NHEAD;
    const int c = blockIdx.x / NHEAD;
    const int t0 = c * 128;
    const float bk = bks[col], bv = bvs[col];

    for (int j = grp; j < 32; j += 4) {
        const size_t rbase = (size_t)(t0 + j * 4) * CDIM + h * 64 + col;
        const float* pk = kkv + rbase;
        const float* pv = vvv + rbase;
        float* ptK = Kt + rbase;
        float* ptV = Vt + rbase;
        float sk = bk, sv = bv;
        #pragma unroll
        for (int u = 0; u < 4; ++u) {
            sk += pk[(size_t)u * CDIM];
            sv += pv[(size_t)u * CDIM];
            ptK[(size_t)u * CDIM] = sk;
            ptV[(size_t)u * CDIM] = sv;
        }
        curK[j][col] = sk - bk; curV[j][col] = sv - bv;
        size_t o = ((size_t)(c * 32 + j) * NHEAD + h) * 64 + col;
        Kset[o] = sk; Vset[o] = sv;
    }
    __syncthreads();

    const int LBASE[6] = {0, 32, 48, 56, 60, 62};
    const int GBASE[6] = {0, 512, 768, 896, 960, 992};
    #pragma unroll
    for (int li = 1; li < 6; ++li) {
        const int ns = 32 >> li;
        for (int j = grp; j < ns; j += 4) {
            float sk = curK[LBASE[li - 1] + 2 * j][col] + curK[LBASE[li - 1] + 2 * j + 1][col];
            float sv = curV[LBASE[li - 1] + 2 * j][col] + curV[LBASE[li - 1] + 2 * j + 1][col];
            curK[LBASE[li] + j][col] = sk; curV[LBASE[li] + j][col] = sv;
            size_t o = ((size_t)(GBASE[li] + c * ns + j) * NHEAD + h) * 64 + col;
            Kset[o] = sk + bk; Vset[o] = sv + bv;
        }
        __syncthreads();
    }

    if (grp == 0) {
        scrK[((size_t)h * 16 + c) * 64 + col] = curK[62][col];
        scrV[((size_t)h * 16 + c) * 64 + col] = curV[62][col];
    }
}

__global__ __launch_bounds__(256) void set_upper(
    const float* __restrict__ scrK, const float* __restrict__ scrV,
    const float* __restrict__ bks, const float* __restrict__ bvs,
    float* __restrict__ Kset, float* __restrict__ Vset)
{
    __shared__ float cK[15][64], cV[15][64];
    const int h = blockIdx.x;
    const int tid = threadIdx.x, col = tid & 63, grp = tid >> 6;
    const float bk = bks[col], bv = bvs[col];

    for (int j = grp; j < 8; j += 4) {
        float sk = scrK[((size_t)h * 16 + 2 * j) * 64 + col] + scrK[((size_t)h * 16 + 2 * j + 1) * 64 + col];
        float sv = scrV[((size_t)h * 16 + 2 * j) * 64 + col] + scrV[((size_t)h * 16 + 2 * j + 1) * 64 + col];
        cK[j][col] = sk; cV[j][col] = sv;
        size_t o = ((size_t)(1008 + j) * NHEAD + h) * 64 + col;
        Kset[o] = sk + bk; Vset[o] = sv + bv;
    }
    __syncthreads();
    const int LB[4] = {0, 8, 12, 14};
    const int GB[4] = {1008, 1016, 1020, 1022};
    #pragma unroll
    for (int li = 1; li < 4; ++li) {
        const int ns = 8 >> li;
        for (int j = grp; j < ns; j += 4) {
            float sk = cK[LB[li - 1] + 2 * j][col] + cK[LB[li - 1] + 2 * j + 1][col];
            float sv = cV[LB[li - 1] + 2 * j][col] + cV[LB[li - 1] + 2 * j + 1][col];
            cK[LB[li] + j][col] = sk; cV[LB[li] + j][col] = sv;
            size_t o = ((size_t)(GB[li] + j) * NHEAD + h) * 64 + col;
            Kset[o] = sk + bk; Vset[o] = sv + bv;
        }
        __syncthreads();
    }
}

// ---------- MFMA flash attention ----------
__global__ __launch_bounds__(256, 3) void attn_mfma(
    const float* __restrict__ qbuf, const float* __restrict__ Kset,
    const float* __restrict__ Vset, const float* __restrict__ Ktail,
    const float* __restrict__ Vtail, float* __restrict__ attout)
{
    __shared__ float vS[64][66];
    __shared__ float sS[32][68];
    __shared__ float mrow[32], lrow[32], arow[32];
    __shared__ float red[32][8];
    __shared__ int   sid[64], send[64];

    const int tid = threadIdx.x;
    const int b   = 63 - (blockIdx.x / NHEAD);
    const int h   = blockIdx.x % NHEAD;
    const int T0  = b * 32;
    const int wave = tid >> 6, lane = tid & 63;
    const int lane15 = lane & 15, quad = lane >> 4;

    const int Tend = T0 + 32;
    const int LOFF[10] = {0, 512, 768, 896, 960, 992, 1008, 1016, 1020, 1022};
    int pfx[10], Vtot = 0;
    #pragma unroll
    for (int li = 0; li < 10; ++li) { pfx[li] = Vtot; Vtot += Tend >> (li + 2); }

    short8 Qhi[2][2], Qlo[2][2];
    #pragma unroll
    for (int ms = 0; ms < 2; ++ms)
        #pragma unroll
        for (int kt = 0; kt < 2; ++kt) {
            const float* qp = qbuf + ((size_t)(T0 + ms * 16 + lane15) * NHEAD + h) * 64 + kt * 32 + quad * 8;
            float f[8];
            *(float4*)&f[0] = *(const float4*)qp;
            *(float4*)&f[4] = *(const float4*)(qp + 4);
            split8_bf16(f, Qhi[ms][kt], Qlo[ms][kt]);
        }

    if (tid < 32) { mrow[tid] = -1e30f; lrow[tid] = 0.f; }

    f32x4 oacc[2];
    oacc[0] = (f32x4){0.f, 0.f, 0.f, 0.f};
    oacc[1] = (f32x4){0.f, 0.f, 0.f, 0.f};

    const int ntiles = (Vtot + 63) >> 6;
    const int row = tid >> 3, part = tid & 7;

    for (int tile = 0; tile < ntiles; ++tile) {
        __syncthreads();

        if (tid < 64) {
            int j = tile * 64 + tid;
            int s_ = 0, e_ = 0x7fffffff;
            if (j < Vtot) {
                int li = 0;
                #pragma unroll
                for (int u = 1; u < 10; ++u) if (j >= pfx[u]) li = u;
                int idx = j - pfx[li];
                s_ = LOFF[li] + idx;
                e_ = (idx + 1) << (li + 2);
            }
            sid[tid] = s_; send[tid] = e_;
        }
        __syncthreads();

        #pragma unroll
        for (int i = 0; i < 4; ++i) {
            int s  = (tid >> 4) + 16 * i;
            int d4 = tid & 15;
            *(float4*)&vS[s][d4 * 4] =
                *(const float4*)&Vset[((size_t)sid[s] * NHEAD + h) * 64 + d4 * 4];
        }

        short8 Khi[2], Klo[2];
        {
            const int sK = sid[wave * 16 + lane15];
            const float* kp = Kset + ((size_t)sK * NHEAD + h) * 64 + quad * 8;
            #pragma unroll
            for (int kt = 0; kt < 2; ++kt) {
                float f[8];
                *(float4*)&f[0] = *(const float4*)(kp + kt * 32);
                *(float4*)&f[4] = *(const float4*)(kp + kt * 32 + 4);
                split8_bf16(f, Khi[kt], Klo[kt]);
            }
        }

        f32x4 lacc[2];
        lacc[0] = (f32x4){0.f, 0.f, 0.f, 0.f};
        lacc[1] = (f32x4){0.f, 0.f, 0.f, 0.f};
        #pragma unroll
        for (int kt = 0; kt < 2; ++kt)
            #pragma unroll
            for (int ms = 0; ms < 2; ++ms) {
                lacc[ms] = __builtin_amdgcn_mfma_f32_16x16x32_bf16(Qhi[ms][kt], Khi[kt], lacc[ms], 0, 0, 0);
                lacc[ms] = __builtin_amdgcn_mfma_f32_16x16x32_bf16(Qlo[ms][kt], Khi[kt], lacc[ms], 0, 0, 0);
                lacc[ms] = __builtin_amdgcn_mfma_f32_16x16x32_bf16(Qhi[ms][kt], Klo[kt], lacc[ms], 0, 0, 0);
            }

        {
            const int sendv = send[wave * 16 + lane15];
            #pragma unroll
            for (int ms = 0; ms < 2; ++ms)
                #pragma unroll
                for (int r = 0; r < 4; ++r) {
                    int qrow = ms * 16 + quad * 4 + r;
                    bool ok = (T0 + qrow + 1) >= sendv;
                    sS[qrow][wave * 16 + lane15] = ok ? lacc[ms][r] * 0.125f : -1e30f;
                }
        }
        __syncthreads();

        float4* sr = (float4*)&sS[row][0];
        {
            float4 a = sr[part * 2], c4 = sr[part * 2 + 1];
            float mx = fmaxf(fmaxf(fmaxf(a.x, a.y), fmaxf(a.z, a.w)),
                             fmaxf(fmaxf(c4.x, c4.y), fmaxf(c4.z, c4.w)));
            red[row][part] = mx;
        }
        __syncthreads();
        if (tid < 32) {
            float rmax = red[tid][0];
            #pragma unroll
            for (int u = 1; u < 8; ++u) rmax = fmaxf(rmax, red[tid][u]);
            float mold = mrow[tid];
            float mnew = fmaxf(mold, rmax);
            arow[tid] = __expf(mold - mnew);
            mrow[tid] = mnew;
        }
        __syncthreads();

        {
            const float mn = mrow[row];
            float4 a = sr[part * 2], c4 = sr[part * 2 + 1];
            a.x = a.x > -1e29f ? __expf(a.x - mn) : 0.f;
            a.y = a.y > -1e29f ? __expf(a.y - mn) : 0.f;
            a.z = a.z > -1e29f ? __expf(a.z - mn) : 0.f;
            a.w = a.w > -1e29f ? __expf(a.w - mn) : 0.f;
            c4.x = c4.x > -1e29f ? __expf(c4.x - mn) : 0.f;
            c4.y = c4.y > -1e29f ? __expf(c4.y - mn) : 0.f;
            c4.z = c4.z > -1e29f ? __expf(c4.z - mn) : 0.f;
            c4.w = c4.w > -1e29f ? __expf(c4.w - mn) : 0.f;
            sr[part * 2] = a; sr[part * 2 + 1] = c4;
            red[row][part] = (a.x + a.y + a.z + a.w) + (c4.x + c4.y + c4.z + c4.w);
        }
        __syncthreads();
        if (tid < 32) {
            float t = 0.f;
            #pragma unroll
            for (int u = 0; u < 8; ++u) t += red[tid][u];
            lrow[tid] = arow[tid] * lrow[tid] + t;
        }

        #pragma unroll
        for (int ms = 0; ms < 2; ++ms)
            #pragma unroll
            for (int r = 0; r < 4; ++r)
                oacc[ms][r] *= arow[ms * 16 + quad * 4 + r];
        // (no barrier needed: sS/vS visibility guaranteed by the pass-2 reduction barrier)

        #pragma unroll
        for (int kt = 0; kt < 2; ++kt) {
            short8 Pf[2];
            #pragma unroll
            for (int ms = 0; ms < 2; ++ms) {
                const float* pp = &sS[ms * 16 + lane15][kt * 32 + quad * 8];
                float f[8];
                *(float4*)&f[0] = *(const float4*)pp;
                *(float4*)&f[4] = *(const float4*)(pp + 4);
                unsigned w[4];
                #pragma unroll
                for (int p = 0; p < 4; ++p) w[p] = pack2_bf16_rne(f[2 * p], f[2 * p + 1]);
                Pf[ms] = mk_short8(w);
            }
            unsigned vw[4];
            #pragma unroll
            for (int jp = 0; jp < 4; ++jp) {
                float a = vS[kt * 32 + quad * 8 + 2 * jp][wave * 16 + lane15];
                float bb = vS[kt * 32 + quad * 8 + 2 * jp + 1][wave * 16 + lane15];
                vw[jp] = pack2_bf16_rne(a, bb);
            }
            short8 Vf = mk_short8(vw);
            #pragma unroll
            for (int ms = 0; ms < 2; ++ms)
                oacc[ms] = __builtin_amdgcn_mfma_f32_16x16x32_bf16(Pf[ms], Vf, oacc[ms], 0, 0, 0);
        }
    }

    __syncthreads();

    {
        const float* qr = qbuf  + ((size_t)(T0 + row) * NHEAD + h) * 64;
        const float* kr = Ktail + ((size_t)(T0 + row) * NHEAD + h) * 64;
        float dp = 0.f;
        for (int d = part; d < 64; d += 8) dp += qr[d] * kr[d];
        red[row][part] = dp;
    }
    __syncthreads();
    if (tid < 32) {
        float tl = 0.f;
        #pragma unroll
        for (int u = 0; u < 8; ++u) tl += red[tid][u];
        tl *= 0.125f;
        float mold = mrow[tid];
        float mf = fmaxf(mold, tl);
        float al = __expf(mold - mf);
        float pt = __expf(tl - mf);
        float lf = al * lrow[tid] + pt;
        arow[tid] = al;
        lrow[tid] = pt / lf;
        mrow[tid] = 1.f / lf;
    }
    __syncthreads();

    #pragma unroll
    for (int ms = 0; ms < 2; ++ms)
        #pragma unroll
        for (int r = 0; r < 4; ++r) {
            int qrow = ms * 16 + quad * 4 + r;
            int col = wave * 16 + lane15;
            float al_inv = arow[qrow] * mrow[qrow];
            float ptinv = lrow[qrow];
            size_t base = ((size_t)(T0 + qrow) * NHEAD + h) * 64 + col;
            attout[base] = oacc[ms][r] * al_inv + ptinv * Vtail[base];
        }
}

extern "C" void kernel_launch(void* const* d_in, const int* in_sizes, int n_in,
                              void* d_out, int out_size, void* d_ws, size_t ws_size,
                              hipStream_t stream)
{
    const float* x   = (const float*)d_in[0];
    const float* Wq  = (const float*)d_in[1];
    const float* Wk  = (const float*)d_in[2];
    const float* Wv  = (const float*)d_in[3];
    const float* Wks = (const float*)d_in[4];
    const float* bks = (const float*)d_in[5];
    const float* Wvs = (const float*)d_in[6];
    const float* bvs = (const float*)d_in[7];
    const float* Wc  = (const float*)d_in[8];
    const float* bc  = (const float*)d_in[9];
    float* out = (float*)d_out;

    float* ws = (float*)d_ws;
    const size_t TC = (size_t)TLEN * CDIM;
    float* q      = ws;
    float* k      = q + TC;
    float* v      = k + TC;
    float* kkv    = v + TC;
    float* vvv    = kkv + TC;
    float* Kt     = vvv + TC;
    float* Vt     = Kt + TC;
    float* Kset   = Vt + TC;
    float* Vset   = Kset + (size_t)NSETS * CDIM;
    float* attout = Vset + (size_t)NSETS * CDIM;
    _Float16* WblobMap = (_Float16*)attout;
    _Float16* blobQKV  = (_Float16*)(attout + 262144);
    float* scrK = attout + 1146880;
    float* scrV = scrK + 12 * 16 * 64;
    _Float16* blobC = (_Float16*)k;   // k dead after map_f16

    prep_w768x3<<<3 * 2304, 256, 0, stream>>>(Wq, Wk, Wv, blobQKV);
    prep_w<<<(4096 * 128) / 256, 256, 0, stream>>>(Wks, Wvs, WblobMap);

    gemm_qkv<<<dim3(36, 64), 256, 0, stream>>>(x, blobQKV, q);

    map_f16<<<(TLEN * NHEAD) / 32, 256, 0, stream>>>(k, v, WblobMap, kkv, vvv);

    prep_w768<<<2304, 256, 0, stream>>>(Wc, blobC);

    set_lower<<<16 * NHEAD, 256, 0, stream>>>(kkv, vvv, bks, bvs, Kset, Vset, scrK, scrV, Kt, Vt);
    set_upper<<<NHEAD, 256, 0, stream>>>(scrK, scrV, bks, bvs, Kset, Vset);

    attn_mfma<<<(TLEN / 32) * NHEAD, 256, 0, stream>>>(q, Kset, Vset, Kt, Vt, attout);

    gemm_mfma<0, 1><<<dim3(12, 64), 256, 0, stream>>>(attout, blobC, bc, out, TLEN, CDIM, CDIM);
}

// Round 11
// 277.618 us; speedup vs baseline: 1.0207x; 1.0207x over previous
//
#include <hip/hip_runtime.h>
#include <cstdint>

#define NHEAD 12
#define TLEN 2048
#define CDIM 768
#define NSETS 1023   // 512+256+128+64+32+16+8+4+2+1

typedef __attribute__((ext_vector_type(8))) _Float16 half8;
typedef __attribute__((ext_vector_type(2))) __fp16 fp16x2;
typedef __attribute__((ext_vector_type(8))) short short8;   // 8 bf16
typedef __attribute__((ext_vector_type(4))) float f32x4;

__device__ __forceinline__ float elu1(float x) { return x > 0.f ? x + 1.f : __expf(x); }

__device__ __forceinline__ unsigned pack2_bf16_trunc(float a, float b) {
    unsigned ua = __float_as_uint(a), ub = __float_as_uint(b);
    return __builtin_amdgcn_perm(ub, ua, 0x07060302);
}
__device__ __forceinline__ unsigned pack2_bf16_rne(float a, float b) {
    unsigned ua = __float_as_uint(a), ub = __float_as_uint(b);
    ua = ua + 0x7fff + ((ua >> 16) & 1);
    ub = ub + 0x7fff + ((ub >> 16) & 1);
    return (ub & 0xffff0000u) | (ua >> 16);
}
__device__ __forceinline__ short8 mk_short8(const unsigned* u) {
    union { unsigned w[4]; short8 s; } x;
    x.w[0] = u[0]; x.w[1] = u[1]; x.w[2] = u[2]; x.w[3] = u[3];
    return x.s;
}
__device__ __forceinline__ void split8_bf16(const float* f, short8& hi, short8& lo) {
    unsigned hp[4], lp[4];
    #pragma unroll
    for (int p = 0; p < 4; ++p) {
        float a = f[2 * p], b = f[2 * p + 1];
        unsigned ua = __float_as_uint(a), ub = __float_as_uint(b);
        hp[p] = __builtin_amdgcn_perm(ub, ua, 0x07060302);
        float ra = a - __uint_as_float(ua & 0xffff0000u);
        float rb = b - __uint_as_float(ub & 0xffff0000u);
        lp[p] = pack2_bf16_trunc(ra, rb);
    }
    hi = mk_short8(hp); lo = mk_short8(lp);
}
__device__ __forceinline__ void split8_f16(const float* f, half8& hi, half8& lo) {
    union { fp16x2 h2[4]; half8 h8; } uh, ul;
    #pragma unroll
    for (int jp = 0; jp < 4; ++jp) {
        float a = f[2 * jp], b = f[2 * jp + 1];
        fp16x2 hh = __builtin_amdgcn_cvt_pkrtz(a, b);
        uh.h2[jp] = hh;
        ul.h2[jp] = __builtin_amdgcn_cvt_pkrtz(a - (float)hh[0], b - (float)hh[1]);
    }
    hi = uh.h8; lo = ul.h8;
}

// ---------- prep: 768x768 W -> f16 fragment-major blob ----------
__global__ __launch_bounds__(256) void prep_w768(
    const float* __restrict__ W, _Float16* __restrict__ blob)
{
    const int idx = blockIdx.x * 256 + threadIdx.x;
    const int k = idx / 768, n = idx % 768;
    const int i = k >> 5, kl = k & 31;
    const int quad = kl >> 3, j = kl & 7;
    const int nsg = n >> 4, lane15 = n & 15;
    const int lane = quad * 16 + lane15;
    blob[((size_t)(i * 48 + nsg) * 64 + lane) * 8 + j] = (_Float16)W[idx];
}

// fused Q/K/V prep
__global__ __launch_bounds__(256) void prep_w768x3(
    const float* __restrict__ Wq, const float* __restrict__ Wk,
    const float* __restrict__ Wv, _Float16* __restrict__ blobs)
{
    const int g = blockIdx.x;          // 3*2304
    const int sel = g / 2304;
    const float* W = sel == 0 ? Wq : (sel == 1 ? Wk : Wv);
    _Float16* blob = blobs + (size_t)sel * 589824;
    const int idx = (g % 2304) * 256 + threadIdx.x;
    const int k = idx / 768, n = idx % 768;
    const int i = k >> 5, kl = k & 31;
    const int quad = kl >> 3, j = kl & 7;
    const int nsg = n >> 4, lane15 = n & 15;
    const int lane = quad * 16 + lane15;
    blob[((size_t)(i * 48 + nsg) * 64 + lane) * 8 + j] = (_Float16)W[idx];
}

// ---------- MFMA GEMM core (final projection) ----------
template<int ACT, int BIAS>
__global__ __launch_bounds__(256, 3) void gemm_mfma(
    const float* __restrict__ A, const _Float16* __restrict__ Bblob,
    const float* __restrict__ bias, float* __restrict__ Cmat,
    int M, int N, int K)
{
    __shared__ float As[2][32][68];
    const int tid = threadIdx.x;
    const int wave = tid >> 6, lane = tid & 63;
    const int lane15 = lane & 15, quad = lane >> 4;
    const int m0 = blockIdx.y * 32;
    const int nsgBase = blockIdx.x * 4 + wave;
    const int nchunks = K >> 6;

    const half8* __restrict__ Bc = (const half8*)Bblob;

    #pragma unroll
    for (int u = 0; u < 2; ++u) {
        int c = tid + u * 256;
        int row = c >> 4, col = (c & 15) * 4;
        *(float4*)&As[0][row][col] = *(const float4*)&A[(size_t)(m0 + row) * K + col];
    }
    __syncthreads();

    f32x4 acc[2];
    acc[0] = (f32x4){0.f, 0.f, 0.f, 0.f};
    acc[1] = (f32x4){0.f, 0.f, 0.f, 0.f};

    for (int ch = 0; ch < nchunks; ++ch) {
        const int buf = ch & 1;
        float4 pre[2];
        if (ch + 1 < nchunks) {
            #pragma unroll
            for (int u = 0; u < 2; ++u) {
                int c = tid + u * 256;
                int row = c >> 4, col = (c & 15) * 4;
                pre[u] = *(const float4*)&A[(size_t)(m0 + row) * K + (ch + 1) * 64 + col];
            }
        }
        #pragma unroll
        for (int kt = 0; kt < 2; ++kt) {
            half8 bb = Bc[(size_t)((ch * 2 + kt) * 48 + nsgBase) * 64 + lane];
            #pragma unroll
            for (int ms = 0; ms < 2; ++ms) {
                float f[8];
                *(float4*)&f[0] = *(const float4*)&As[buf][ms * 16 + lane15][kt * 32 + quad * 8];
                *(float4*)&f[4] = *(const float4*)&As[buf][ms * 16 + lane15][kt * 32 + quad * 8 + 4];
                half8 ah, al;
                split8_f16(f, ah, al);
                acc[ms] = __builtin_amdgcn_mfma_f32_16x16x32_f16(ah, bb, acc[ms], 0, 0, 0);
                acc[ms] = __builtin_amdgcn_mfma_f32_16x16x32_f16(al, bb, acc[ms], 0, 0, 0);
            }
        }
        if (ch + 1 < nchunks) {
            #pragma unroll
            for (int u = 0; u < 2; ++u) {
                int c = tid + u * 256;
                int row = c >> 4, col = (c & 15) * 4;
                *(float4*)&As[1 - buf][row][col] = pre[u];
            }
        }
        __syncthreads();
    }

    const int coln = blockIdx.x * 64 + wave * 16 + lane15;
    #pragma unroll
    for (int ms = 0; ms < 2; ++ms)
        #pragma unroll
        for (int r = 0; r < 4; ++r) {
            int row = m0 + ms * 16 + quad * 4 + r;
            float v = acc[ms][r];
            if (BIAS) v += bias[coln];
            if (ACT) v = elu1(v);
            Cmat[(size_t)row * N + coln] = v;
        }
}

// ---------- fused QKV projection ----------
__global__ __launch_bounds__(256, 3) void gemm_qkv(
    const float* __restrict__ A, const _Float16* __restrict__ blobs,
    float* __restrict__ outbase)
{
    __shared__ float As[2][32][68];
    const int which = blockIdx.x / 12;
    const int bx = blockIdx.x % 12;
    const _Float16* Bblob = blobs + (size_t)which * 589824;
    float* Cmat = outbase + (size_t)which * ((size_t)TLEN * CDIM);
    const bool act = which < 2;

    const int tid = threadIdx.x;
    const int wave = tid >> 6, lane = tid & 63;
    const int lane15 = lane & 15, quad = lane >> 4;
    const int m0 = blockIdx.y * 32;
    const int nsgBase = bx * 4 + wave;
    const int nchunks = CDIM >> 6;   // 12

    const half8* __restrict__ Bc = (const half8*)Bblob;

    #pragma unroll
    for (int u = 0; u < 2; ++u) {
        int c = tid + u * 256;
        int row = c >> 4, col = (c & 15) * 4;
        *(float4*)&As[0][row][col] = *(const float4*)&A[(size_t)(m0 + row) * CDIM + col];
    }
    __syncthreads();

    f32x4 acc[2];
    acc[0] = (f32x4){0.f, 0.f, 0.f, 0.f};
    acc[1] = (f32x4){0.f, 0.f, 0.f, 0.f};

    for (int ch = 0; ch < nchunks; ++ch) {
        const int buf = ch & 1;
        float4 pre[2];
        if (ch + 1 < nchunks) {
            #pragma unroll
            for (int u = 0; u < 2; ++u) {
                int c = tid + u * 256;
                int row = c >> 4, col = (c & 15) * 4;
                pre[u] = *(const float4*)&A[(size_t)(m0 + row) * CDIM + (ch + 1) * 64 + col];
            }
        }
        #pragma unroll
        for (int kt = 0; kt < 2; ++kt) {
            half8 bb = Bc[(size_t)((ch * 2 + kt) * 48 + nsgBase) * 64 + lane];
            #pragma unroll
            for (int ms = 0; ms < 2; ++ms) {
                float f[8];
                *(float4*)&f[0] = *(const float4*)&As[buf][ms * 16 + lane15][kt * 32 + quad * 8];
                *(float4*)&f[4] = *(const float4*)&As[buf][ms * 16 + lane15][kt * 32 + quad * 8 + 4];
                half8 ah, al;
                split8_f16(f, ah, al);
                acc[ms] = __builtin_amdgcn_mfma_f32_16x16x32_f16(ah, bb, acc[ms], 0, 0, 0);
                acc[ms] = __builtin_amdgcn_mfma_f32_16x16x32_f16(al, bb, acc[ms], 0, 0, 0);
            }
        }
        if (ch + 1 < nchunks) {
            #pragma unroll
            for (int u = 0; u < 2; ++u) {
                int c = tid + u * 256;
                int row = c >> 4, col = (c & 15) * 4;
                *(float4*)&As[1 - buf][row][col] = pre[u];
            }
        }
        __syncthreads();
    }

    const int coln = bx * 64 + wave * 16 + lane15;
    #pragma unroll
    for (int ms = 0; ms < 2; ++ms)
        #pragma unroll
        for (int r = 0; r < 4; ++r) {
            int row = m0 + ms * 16 + quad * 4 + r;
            float v = acc[ms][r];
            if (act) v = elu1(v);
            Cmat[(size_t)row * CDIM + coln] = v;
        }
}

// ---------- prep: map W -> f16 fragment-major blob (4096x128) ----------
__global__ __launch_bounds__(256) void prep_w(
    const float* __restrict__ Wks, const float* __restrict__ Wvs,
    _Float16* __restrict__ Wblob)
{
    const int idx = blockIdx.x * 256 + threadIdx.x;
    const int kk = idx >> 7, n = idx & 127;
    float f = (n < 64) ? Wks[(size_t)kk * 64 + n] : Wvs[(size_t)kk * 64 + (n - 64)];
    const int i = kk >> 6, kl = kk & 63;
    const int ks = kl >> 5, quad = (kl >> 3) & 3, j = kl & 7;
    const int nsg = n >> 4, lane15 = n & 15;
    const int lane = quad * 16 + lane15;
    const size_t off = ((size_t)(((i * 2 + ks) * 8 + nsg)) * 64 + lane) * 8 + j;
    Wblob[off] = (_Float16)f;
}

// ---------- MFMA mapped features v4: single-f16 A (1 MFMA/step), pipelined B/K ----------
__global__ __launch_bounds__(256, 3) void map_f16(
    const float* __restrict__ kbuf, const float* __restrict__ vbuf,
    const _Float16* __restrict__ Wblob,
    float* __restrict__ kkv, float* __restrict__ vvv)
{
    __shared__ float kS[32][68];

    const int tid = threadIdx.x;
    const int p0 = blockIdx.x * 32;
    const int wave = tid >> 6, lane = tid & 63;
    const int lane15 = lane & 15, quad = lane >> 4;
    const int mh = wave & 1;    // position half
    const int nh = wave >> 1;   // output half: 0 -> kkv cols, 1 -> vvv cols

    #pragma unroll
    for (int u = 0; u < 2; ++u) {
        int c = tid + u * 256;
        int row = c >> 4, col = (c & 15) * 4;
        *(float4*)&kS[row][col] = *(const float4*)&kbuf[(size_t)(p0 + row) * 64 + col];
    }

    float vr[2][8];
    {
        const size_t pbase = (size_t)(p0 + mh * 16 + lane15) * 64;
        #pragma unroll
        for (int ks = 0; ks < 2; ++ks) {
            *(float4*)&vr[ks][0] = *(const float4*)&vbuf[pbase + ks * 32 + quad * 8];
            *(float4*)&vr[ks][4] = *(const float4*)&vbuf[pbase + ks * 32 + quad * 8 + 4];
        }
    }
    __syncthreads();

    const half8* __restrict__ Wc = (const half8*)Wblob;

    f32x4 acc[4];
    #pragma unroll
    for (int nsl = 0; nsl < 4; ++nsl) acc[nsl] = (f32x4){0.f, 0.f, 0.f, 0.f};

    half8 b0[4], b1[4], b2[4], b3[4];
    float k0, k1, k2, k3;

    auto loadB = [&](half8* b, int s) {
        #pragma unroll
        for (int nsl = 0; nsl < 4; ++nsl)
            b[nsl] = Wc[(size_t)(s * 8 + nh * 4 + nsl) * 64 + lane];
    };
    auto loadK = [&](float& kf, int s) { kf = kS[mh * 16 + lane15][s >> 1]; };
    auto compute = [&](const half8* b, float kf, int s) {
        const int ks = s & 1;
        union { fp16x2 h2[4]; half8 h8; } uh;
        #pragma unroll
        for (int jp = 0; jp < 4; ++jp)
            uh.h2[jp] = __builtin_amdgcn_cvt_pkrtz(kf * vr[ks][2 * jp], kf * vr[ks][2 * jp + 1]);
        half8 ah = uh.h8;
        #pragma unroll
        for (int nsl = 0; nsl < 4; ++nsl)
            acc[nsl] = __builtin_amdgcn_mfma_f32_16x16x32_f16(ah, b[nsl], acc[nsl], 0, 0, 0);
    };

    loadB(b0, 0); loadB(b1, 1); loadB(b2, 2); loadB(b3, 3);
    loadK(k0, 0); loadK(k1, 1); loadK(k2, 2); loadK(k3, 3);
    for (int s = 0; s < 128; s += 4) {
        const bool more = (s + 4) < 128;
        compute(b0, k0, s);
        compute(b1, k1, s + 1);
        if (more) { loadB(b0, s + 4); loadK(k0, s + 4); loadB(b1, s + 5); loadK(k1, s + 5); }
        compute(b2, k2, s + 2);
        compute(b3, k3, s + 3);
        if (more) { loadB(b2, s + 6); loadK(k2, s + 6); loadB(b3, s + 7); loadK(k3, s + 7); }
    }

    // epilogue: C/D layout col=lane15, row=quad*4+r
    float* dst = nh ? vvv : kkv;
    #pragma unroll
    for (int nsl = 0; nsl < 4; ++nsl)
        #pragma unroll
        for (int r = 0; r < 4; ++r) {
            int p = p0 + mh * 16 + quad * 4 + r;
            int col = nsl * 16 + lane15;
            dst[(size_t)p * 64 + col] = acc[nsl][r];
        }
}

// ---------- set features (levels 2..7) + fused tail cumsum ----------
__global__ __launch_bounds__(256) void set_lower(
    const float* __restrict__ kkv, const float* __restrict__ vvv,
    const float* __restrict__ bks, const float* __restrict__ bvs,
    float* __restrict__ Kset, float* __restrict__ Vset,
    float* __restrict__ scrK, float* __restrict__ scrV,
    float* __restrict__ Kt, float* __restrict__ Vt)
{
    __shared__ float curK[63][64];
    __shared__ float curV[63][64];
    const int tid = threadIdx.x;
    const int col = tid & 63, grp = tid >> 6;
    const int h = blockIdx.x % NHEAD;
    const int c = blockIdx.x / NHEAD;
    const int t0 = c * 128;
    const float bk = bks[col], bv = bvs[col];

    for (int j = grp; j < 32; j += 4) {
        const size_t rbase = (size_t)(t0 + j * 4) * CDIM + h * 64 + col;
        const float* pk = kkv + rbase;
        const float* pv = vvv + rbase;
        float* ptK = Kt + rbase;
        float* ptV = Vt + rbase;
        float sk = bk, sv = bv;
        #pragma unroll
        for (int u = 0; u < 4; ++u) {
            sk += pk[(size_t)u * CDIM];
            sv += pv[(size_t)u * CDIM];
            ptK[(size_t)u * CDIM] = sk;
            ptV[(size_t)u * CDIM] = sv;
        }
        curK[j][col] = sk - bk; curV[j][col] = sv - bv;
        size_t o = ((size_t)(c * 32 + j) * NHEAD + h) * 64 + col;
        Kset[o] = sk; Vset[o] = sv;
    }
    __syncthreads();

    const int LBASE[6] = {0, 32, 48, 56, 60, 62};
    const int GBASE[6] = {0, 512, 768, 896, 960, 992};
    #pragma unroll
    for (int li = 1; li < 6; ++li) {
        const int ns = 32 >> li;
        for (int j = grp; j < ns; j += 4) {
            float sk = curK[LBASE[li - 1] + 2 * j][col] + curK[LBASE[li - 1] + 2 * j + 1][col];
            float sv = curV[LBASE[li - 1] + 2 * j][col] + curV[LBASE[li - 1] + 2 * j + 1][col];
            curK[LBASE[li] + j][col] = sk; curV[LBASE[li] + j][col] = sv;
            size_t o = ((size_t)(GBASE[li] + c * ns + j) * NHEAD + h) * 64 + col;
            Kset[o] = sk + bk; Vset[o] = sv + bv;
        }
        __syncthreads();
    }

    if (grp == 0) {
        scrK[((size_t)h * 16 + c) * 64 + col] = curK[62][col];
        scrV[((size_t)h * 16 + c) * 64 + col] = curV[62][col];
    }
}

__global__ __launch_bounds__(256) void set_upper(
    const float* __restrict__ scrK, const float* __restrict__ scrV,
    const float* __restrict__ bks, const float* __restrict__ bvs,
    float* __restrict__ Kset, float* __restrict__ Vset)
{
    __shared__ float cK[15][64], cV[15][64];
    const int h = blockIdx.x;
    const int tid = threadIdx.x, col = tid & 63, grp = tid >> 6;
    const float bk = bks[col], bv = bvs[col];

    for (int j = grp; j < 8; j += 4) {
        float sk = scrK[((size_t)h * 16 + 2 * j) * 64 + col] + scrK[((size_t)h * 16 + 2 * j + 1) * 64 + col];
        float sv = scrV[((size_t)h * 16 + 2 * j) * 64 + col] + scrV[((size_t)h * 16 + 2 * j + 1) * 64 + col];
        cK[j][col] = sk; cV[j][col] = sv;
        size_t o = ((size_t)(1008 + j) * NHEAD + h) * 64 + col;
        Kset[o] = sk + bk; Vset[o] = sv + bv;
    }
    __syncthreads();
    const int LB[4] = {0, 8, 12, 14};
    const int GB[4] = {1008, 1016, 1020, 1022};
    #pragma unroll
    for (int li = 1; li < 4; ++li) {
        const int ns = 8 >> li;
        for (int j = grp; j < ns; j += 4) {
            float sk = cK[LB[li - 1] + 2 * j][col] + cK[LB[li - 1] + 2 * j + 1][col];
            float sv = cV[LB[li - 1] + 2 * j][col] + cV[LB[li - 1] + 2 * j + 1][col];
            cK[LB[li] + j][col] = sk; cV[LB[li] + j][col] = sv;
            size_t o = ((size_t)(GB[li] + j) * NHEAD + h) * 64 + col;
            Kset[o] = sk + bk; Vset[o] = sv + bv;
        }
        __syncthreads();
    }
}

// ---------- MFMA flash attention ----------
__global__ __launch_bounds__(256, 3) void attn_mfma(
    const float* __restrict__ qbuf, const float* __restrict__ Kset,
    const float* __restrict__ Vset, const float* __restrict__ Ktail,
    const float* __restrict__ Vtail, float* __restrict__ attout)
{
    __shared__ float vS[64][66];
    __shared__ float sS[32][68];
    __shared__ float mrow[32], lrow[32], arow[32];
    __shared__ float red[32][8];
    __shared__ int   sid[64], send[64];

    const int tid = threadIdx.x;
    const int b   = 63 - (blockIdx.x / NHEAD);
    const int h   = blockIdx.x % NHEAD;
    const int T0  = b * 32;
    const int wave = tid >> 6, lane = tid & 63;
    const int lane15 = lane & 15, quad = lane >> 4;

    const int Tend = T0 + 32;
    const int LOFF[10] = {0, 512, 768, 896, 960, 992, 1008, 1016, 1020, 1022};
    int pfx[10], Vtot = 0;
    #pragma unroll
    for (int li = 0; li < 10; ++li) { pfx[li] = Vtot; Vtot += Tend >> (li + 2); }

    short8 Qhi[2][2], Qlo[2][2];
    #pragma unroll
    for (int ms = 0; ms < 2; ++ms)
        #pragma unroll
        for (int kt = 0; kt < 2; ++kt) {
            const float* qp = qbuf + ((size_t)(T0 + ms * 16 + lane15) * NHEAD + h) * 64 + kt * 32 + quad * 8;
            float f[8];
            *(float4*)&f[0] = *(const float4*)qp;
            *(float4*)&f[4] = *(const float4*)(qp + 4);
            split8_bf16(f, Qhi[ms][kt], Qlo[ms][kt]);
        }

    if (tid < 32) { mrow[tid] = -1e30f; lrow[tid] = 0.f; }

    f32x4 oacc[2];
    oacc[0] = (f32x4){0.f, 0.f, 0.f, 0.f};
    oacc[1] = (f32x4){0.f, 0.f, 0.f, 0.f};

    const int ntiles = (Vtot + 63) >> 6;
    const int row = tid >> 3, part = tid & 7;

    for (int tile = 0; tile < ntiles; ++tile) {
        __syncthreads();

        if (tid < 64) {
            int j = tile * 64 + tid;
            int s_ = 0, e_ = 0x7fffffff;
            if (j < Vtot) {
                int li = 0;
                #pragma unroll
                for (int u = 1; u < 10; ++u) if (j >= pfx[u]) li = u;
                int idx = j - pfx[li];
                s_ = LOFF[li] + idx;
                e_ = (idx + 1) << (li + 2);
            }
            sid[tid] = s_; send[tid] = e_;
        }
        __syncthreads();

        #pragma unroll
        for (int i = 0; i < 4; ++i) {
            int s  = (tid >> 4) + 16 * i;
            int d4 = tid & 15;
            *(float4*)&vS[s][d4 * 4] =
                *(const float4*)&Vset[((size_t)sid[s] * NHEAD + h) * 64 + d4 * 4];
        }

        short8 Khi[2], Klo[2];
        {
            const int sK = sid[wave * 16 + lane15];
            const float* kp = Kset + ((size_t)sK * NHEAD + h) * 64 + quad * 8;
            #pragma unroll
            for (int kt = 0; kt < 2; ++kt) {
                float f[8];
                *(float4*)&f[0] = *(const float4*)(kp + kt * 32);
                *(float4*)&f[4] = *(const float4*)(kp + kt * 32 + 4);
                split8_bf16(f, Khi[kt], Klo[kt]);
            }
        }

        f32x4 lacc[2];
        lacc[0] = (f32x4){0.f, 0.f, 0.f, 0.f};
        lacc[1] = (f32x4){0.f, 0.f, 0.f, 0.f};
        #pragma unroll
        for (int kt = 0; kt < 2; ++kt)
            #pragma unroll
            for (int ms = 0; ms < 2; ++ms) {
                lacc[ms] = __builtin_amdgcn_mfma_f32_16x16x32_bf16(Qhi[ms][kt], Khi[kt], lacc[ms], 0, 0, 0);
                lacc[ms] = __builtin_amdgcn_mfma_f32_16x16x32_bf16(Qlo[ms][kt], Khi[kt], lacc[ms], 0, 0, 0);
                lacc[ms] = __builtin_amdgcn_mfma_f32_16x16x32_bf16(Qhi[ms][kt], Klo[kt], lacc[ms], 0, 0, 0);
            }

        {
            const int sendv = send[wave * 16 + lane15];
            #pragma unroll
            for (int ms = 0; ms < 2; ++ms)
                #pragma unroll
                for (int r = 0; r < 4; ++r) {
                    int qrow = ms * 16 + quad * 4 + r;
                    bool ok = (T0 + qrow + 1) >= sendv;
                    sS[qrow][wave * 16 + lane15] = ok ? lacc[ms][r] * 0.125f : -1e30f;
                }
        }
        __syncthreads();

        float4* sr = (float4*)&sS[row][0];
        {
            float4 a = sr[part * 2], c4 = sr[part * 2 + 1];
            float mx = fmaxf(fmaxf(fmaxf(a.x, a.y), fmaxf(a.z, a.w)),
                             fmaxf(fmaxf(c4.x, c4.y), fmaxf(c4.z, c4.w)));
            red[row][part] = mx;
        }
        __syncthreads();
        if (tid < 32) {
            float rmax = red[tid][0];
            #pragma unroll
            for (int u = 1; u < 8; ++u) rmax = fmaxf(rmax, red[tid][u]);
            float mold = mrow[tid];
            float mnew = fmaxf(mold, rmax);
            arow[tid] = __expf(mold - mnew);
            mrow[tid] = mnew;
        }
        __syncthreads();

        {
            const float mn = mrow[row];
            float4 a = sr[part * 2], c4 = sr[part * 2 + 1];
            a.x = a.x > -1e29f ? __expf(a.x - mn) : 0.f;
            a.y = a.y > -1e29f ? __expf(a.y - mn) : 0.f;
            a.z = a.z > -1e29f ? __expf(a.z - mn) : 0.f;
            a.w = a.w > -1e29f ? __expf(a.w - mn) : 0.f;
            c4.x = c4.x > -1e29f ? __expf(c4.x - mn) : 0.f;
            c4.y = c4.y > -1e29f ? __expf(c4.y - mn) : 0.f;
            c4.z = c4.z > -1e29f ? __expf(c4.z - mn) : 0.f;
            c4.w = c4.w > -1e29f ? __expf(c4.w - mn) : 0.f;
            sr[part * 2] = a; sr[part * 2 + 1] = c4;
            red[row][part] = (a.x + a.y + a.z + a.w) + (c4.x + c4.y + c4.z + c4.w);
        }
        __syncthreads();
        if (tid < 32) {
            float t = 0.f;
            #pragma unroll
            for (int u = 0; u < 8; ++u) t += red[tid][u];
            lrow[tid] = arow[tid] * lrow[tid] + t;
        }

        #pragma unroll
        for (int ms = 0; ms < 2; ++ms)
            #pragma unroll
            for (int r = 0; r < 4; ++r)
                oacc[ms][r] *= arow[ms * 16 + quad * 4 + r];
        // (no barrier needed: sS/vS visibility guaranteed by the pass-2 reduction barrier)

        #pragma unroll
        for (int kt = 0; kt < 2; ++kt) {
            short8 Pf[2];
            #pragma unroll
            for (int ms = 0; ms < 2; ++ms) {
                const float* pp = &sS[ms * 16 + lane15][kt * 32 + quad * 8];
                float f[8];
                *(float4*)&f[0] = *(const float4*)pp;
                *(float4*)&f[4] = *(const float4*)(pp + 4);
                unsigned w[4];
                #pragma unroll
                for (int p = 0; p < 4; ++p) w[p] = pack2_bf16_rne(f[2 * p], f[2 * p + 1]);
                Pf[ms] = mk_short8(w);
            }
            unsigned vw[4];
            #pragma unroll
            for (int jp = 0; jp < 4; ++jp) {
                float a = vS[kt * 32 + quad * 8 + 2 * jp][wave * 16 + lane15];
                float bb = vS[kt * 32 + quad * 8 + 2 * jp + 1][wave * 16 + lane15];
                vw[jp] = pack2_bf16_rne(a, bb);
            }
            short8 Vf = mk_short8(vw);
            #pragma unroll
            for (int ms = 0; ms < 2; ++ms)
                oacc[ms] = __builtin_amdgcn_mfma_f32_16x16x32_bf16(Pf[ms], Vf, oacc[ms], 0, 0, 0);
        }
    }

    __syncthreads();

    {
        const float* qr = qbuf  + ((size_t)(T0 + row) * NHEAD + h) * 64;
        const float* kr = Ktail + ((size_t)(T0 + row) * NHEAD + h) * 64;
        float dp = 0.f;
        for (int d = part; d < 64; d += 8) dp += qr[d] * kr[d];
        red[row][part] = dp;
    }
    __syncthreads();
    if (tid < 32) {
        float tl = 0.f;
        #pragma unroll
        for (int u = 0; u < 8; ++u) tl += red[tid][u];
        tl *= 0.125f;
        float mold = mrow[tid];
        float mf = fmaxf(mold, tl);
        float al = __expf(mold - mf);
        float pt = __expf(tl - mf);
        float lf = al * lrow[tid] + pt;
        arow[tid] = al;
        lrow[tid] = pt / lf;
        mrow[tid] = 1.f / lf;
    }
    __syncthreads();

    #pragma unroll
    for (int ms = 0; ms < 2; ++ms)
        #pragma unroll
        for (int r = 0; r < 4; ++r) {
            int qrow = ms * 16 + quad * 4 + r;
            int col = wave * 16 + lane15;
            float al_inv = arow[qrow] * mrow[qrow];
            float ptinv = lrow[qrow];
            size_t base = ((size_t)(T0 + qrow) * NHEAD + h) * 64 + col;
            attout[base] = oacc[ms][r] * al_inv + ptinv * Vtail[base];
        }
}

extern "C" void kernel_launch(void* const* d_in, const int* in_sizes, int n_in,
                              void* d_out, int out_size, void* d_ws, size_t ws_size,
                              hipStream_t stream)
{
    const float* x   = (const float*)d_in[0];
    const float* Wq  = (const float*)d_in[1];
    const float* Wk  = (const float*)d_in[2];
    const float* Wv  = (const float*)d_in[3];
    const float* Wks = (const float*)d_in[4];
    const float* bks = (const float*)d_in[5];
    const float* Wvs = (const float*)d_in[6];
    const float* bvs = (const float*)d_in[7];
    const float* Wc  = (const float*)d_in[8];
    const float* bc  = (const float*)d_in[9];
    float* out = (float*)d_out;

    float* ws = (float*)d_ws;
    const size_t TC = (size_t)TLEN * CDIM;
    float* q      = ws;
    float* k      = q + TC;
    float* v      = k + TC;
    float* kkv    = v + TC;
    float* vvv    = kkv + TC;
    float* Kt     = vvv + TC;
    float* Vt     = Kt + TC;
    float* Kset   = Vt + TC;
    float* Vset   = Kset + (size_t)NSETS * CDIM;
    float* attout = Vset + (size_t)NSETS * CDIM;
    _Float16* WblobMap = (_Float16*)attout;
    _Float16* blobQKV  = (_Float16*)(attout + 262144);
    float* scrK = attout + 1146880;
    float* scrV = scrK + 12 * 16 * 64;
    _Float16* blobC = (_Float16*)k;   // k dead after map_f16

    prep_w768x3<<<3 * 2304, 256, 0, stream>>>(Wq, Wk, Wv, blobQKV);
    prep_w<<<(4096 * 128) / 256, 256, 0, stream>>>(Wks, Wvs, WblobMap);

    gemm_qkv<<<dim3(36, 64), 256, 0, stream>>>(x, blobQKV, q);

    map_f16<<<(TLEN * NHEAD) / 32, 256, 0, stream>>>(k, v, WblobMap, kkv, vvv);

    prep_w768<<<2304, 256, 0, stream>>>(Wc, blobC);

    set_lower<<<16 * NHEAD, 256, 0, stream>>>(kkv, vvv, bks, bvs, Kset, Vset, scrK, scrV, Kt, Vt);
    set_upper<<<NHEAD, 256, 0, stream>>>(scrK, scrV, bks, bvs, Kset, Vset);

    attn_mfma<<<(TLEN / 32) * NHEAD, 256, 0, stream>>>(q, Kset, Vset, Kt, Vt, attout);

    gemm_mfma<0, 1><<<dim3(12, 64), 256, 0, stream>>>(attout, blobC, bc, out, TLEN, CDIM, CDIM);
}

// Round 12
// 257.698 us; speedup vs baseline: 1.0996x; 1.0773x over previous
//
#include <hip/hip_runtime.h>
#include <cstdint>

#define NHEAD 12
#define TLEN 2048
#define CDIM 768
#define NSETS 1023   // 512+256+128+64+32+16+8+4+2+1

typedef __attribute__((ext_vector_type(8))) _Float16 half8;
typedef __attribute__((ext_vector_type(2))) __fp16 fp16x2;
typedef __attribute__((ext_vector_type(8))) short short8;   // 8 bf16
typedef __attribute__((ext_vector_type(4))) float f32x4;

__device__ __forceinline__ float elu1(float x) { return x > 0.f ? x + 1.f : __expf(x); }

__device__ __forceinline__ unsigned pack2_bf16_trunc(float a, float b) {
    unsigned ua = __float_as_uint(a), ub = __float_as_uint(b);
    return __builtin_amdgcn_perm(ub, ua, 0x07060302);
}
__device__ __forceinline__ unsigned pack2_bf16_rne(float a, float b) {
    unsigned ua = __float_as_uint(a), ub = __float_as_uint(b);
    ua = ua + 0x7fff + ((ua >> 16) & 1);
    ub = ub + 0x7fff + ((ub >> 16) & 1);
    return (ub & 0xffff0000u) | (ua >> 16);
}
__device__ __forceinline__ short8 mk_short8(const unsigned* u) {
    union { unsigned w[4]; short8 s; } x;
    x.w[0] = u[0]; x.w[1] = u[1]; x.w[2] = u[2]; x.w[3] = u[3];
    return x.s;
}
__device__ __forceinline__ void split8_bf16(const float* f, short8& hi, short8& lo) {
    unsigned hp[4], lp[4];
    #pragma unroll
    for (int p = 0; p < 4; ++p) {
        float a = f[2 * p], b = f[2 * p + 1];
        unsigned ua = __float_as_uint(a), ub = __float_as_uint(b);
        hp[p] = __builtin_amdgcn_perm(ub, ua, 0x07060302);
        float ra = a - __uint_as_float(ua & 0xffff0000u);
        float rb = b - __uint_as_float(ub & 0xffff0000u);
        lp[p] = pack2_bf16_trunc(ra, rb);
    }
    hi = mk_short8(hp); lo = mk_short8(lp);
}
__device__ __forceinline__ void split8_f16(const float* f, half8& hi, half8& lo) {
    union { fp16x2 h2[4]; half8 h8; } uh, ul;
    #pragma unroll
    for (int jp = 0; jp < 4; ++jp) {
        float a = f[2 * jp], b = f[2 * jp + 1];
        fp16x2 hh = __builtin_amdgcn_cvt_pkrtz(a, b);
        uh.h2[jp] = hh;
        ul.h2[jp] = __builtin_amdgcn_cvt_pkrtz(a - (float)hh[0], b - (float)hh[1]);
    }
    hi = uh.h8; lo = ul.h8;
}

// ---------- prep: 768x768 W -> f16 fragment-major blob ----------
__global__ __launch_bounds__(256) void prep_w768(
    const float* __restrict__ W, _Float16* __restrict__ blob)
{
    const int idx = blockIdx.x * 256 + threadIdx.x;
    const int k = idx / 768, n = idx % 768;
    const int i = k >> 5, kl = k & 31;
    const int quad = kl >> 3, j = kl & 7;
    const int nsg = n >> 4, lane15 = n & 15;
    const int lane = quad * 16 + lane15;
    blob[((size_t)(i * 48 + nsg) * 64 + lane) * 8 + j] = (_Float16)W[idx];
}

// fused Q/K/V prep
__global__ __launch_bounds__(256) void prep_w768x3(
    const float* __restrict__ Wq, const float* __restrict__ Wk,
    const float* __restrict__ Wv, _Float16* __restrict__ blobs)
{
    const int g = blockIdx.x;          // 3*2304
    const int sel = g / 2304;
    const float* W = sel == 0 ? Wq : (sel == 1 ? Wk : Wv);
    _Float16* blob = blobs + (size_t)sel * 589824;
    const int idx = (g % 2304) * 256 + threadIdx.x;
    const int k = idx / 768, n = idx % 768;
    const int i = k >> 5, kl = k & 31;
    const int quad = kl >> 3, j = kl & 7;
    const int nsg = n >> 4, lane15 = n & 15;
    const int lane = quad * 16 + lane15;
    blob[((size_t)(i * 48 + nsg) * 64 + lane) * 8 + j] = (_Float16)W[idx];
}

// ---------- MFMA GEMM core (final projection) ----------
template<int ACT, int BIAS>
__global__ __launch_bounds__(256, 3) void gemm_mfma(
    const float* __restrict__ A, const _Float16* __restrict__ Bblob,
    const float* __restrict__ bias, float* __restrict__ Cmat,
    int M, int N, int K)
{
    __shared__ float As[2][32][68];
    const int tid = threadIdx.x;
    const int wave = tid >> 6, lane = tid & 63;
    const int lane15 = lane & 15, quad = lane >> 4;
    const int m0 = blockIdx.y * 32;
    const int nsgBase = blockIdx.x * 4 + wave;
    const int nchunks = K >> 6;

    const half8* __restrict__ Bc = (const half8*)Bblob;

    #pragma unroll
    for (int u = 0; u < 2; ++u) {
        int c = tid + u * 256;
        int row = c >> 4, col = (c & 15) * 4;
        *(float4*)&As[0][row][col] = *(const float4*)&A[(size_t)(m0 + row) * K + col];
    }
    __syncthreads();

    f32x4 acc[2];
    acc[0] = (f32x4){0.f, 0.f, 0.f, 0.f};
    acc[1] = (f32x4){0.f, 0.f, 0.f, 0.f};

    for (int ch = 0; ch < nchunks; ++ch) {
        const int buf = ch & 1;
        float4 pre[2];
        if (ch + 1 < nchunks) {
            #pragma unroll
            for (int u = 0; u < 2; ++u) {
                int c = tid + u * 256;
                int row = c >> 4, col = (c & 15) * 4;
                pre[u] = *(const float4*)&A[(size_t)(m0 + row) * K + (ch + 1) * 64 + col];
            }
        }
        #pragma unroll
        for (int kt = 0; kt < 2; ++kt) {
            half8 bb = Bc[(size_t)((ch * 2 + kt) * 48 + nsgBase) * 64 + lane];
            #pragma unroll
            for (int ms = 0; ms < 2; ++ms) {
                float f[8];
                *(float4*)&f[0] = *(const float4*)&As[buf][ms * 16 + lane15][kt * 32 + quad * 8];
                *(float4*)&f[4] = *(const float4*)&As[buf][ms * 16 + lane15][kt * 32 + quad * 8 + 4];
                half8 ah, al;
                split8_f16(f, ah, al);
                acc[ms] = __builtin_amdgcn_mfma_f32_16x16x32_f16(ah, bb, acc[ms], 0, 0, 0);
                acc[ms] = __builtin_amdgcn_mfma_f32_16x16x32_f16(al, bb, acc[ms], 0, 0, 0);
            }
        }
        if (ch + 1 < nchunks) {
            #pragma unroll
            for (int u = 0; u < 2; ++u) {
                int c = tid + u * 256;
                int row = c >> 4, col = (c & 15) * 4;
                *(float4*)&As[1 - buf][row][col] = pre[u];
            }
        }
        __syncthreads();
    }

    const int coln = blockIdx.x * 64 + wave * 16 + lane15;
    #pragma unroll
    for (int ms = 0; ms < 2; ++ms)
        #pragma unroll
        for (int r = 0; r < 4; ++r) {
            int row = m0 + ms * 16 + quad * 4 + r;
            float v = acc[ms][r];
            if (BIAS) v += bias[coln];
            if (ACT) v = elu1(v);
            Cmat[(size_t)row * N + coln] = v;
        }
}

// ---------- fused QKV projection ----------
__global__ __launch_bounds__(256, 3) void gemm_qkv(
    const float* __restrict__ A, const _Float16* __restrict__ blobs,
    float* __restrict__ outbase)
{
    __shared__ float As[2][32][68];
    const int which = blockIdx.x / 12;
    const int bx = blockIdx.x % 12;
    const _Float16* Bblob = blobs + (size_t)which * 589824;
    float* Cmat = outbase + (size_t)which * ((size_t)TLEN * CDIM);
    const bool act = which < 2;

    const int tid = threadIdx.x;
    const int wave = tid >> 6, lane = tid & 63;
    const int lane15 = lane & 15, quad = lane >> 4;
    const int m0 = blockIdx.y * 32;
    const int nsgBase = bx * 4 + wave;
    const int nchunks = CDIM >> 6;   // 12

    const half8* __restrict__ Bc = (const half8*)Bblob;

    #pragma unroll
    for (int u = 0; u < 2; ++u) {
        int c = tid + u * 256;
        int row = c >> 4, col = (c & 15) * 4;
        *(float4*)&As[0][row][col] = *(const float4*)&A[(size_t)(m0 + row) * CDIM + col];
    }
    __syncthreads();

    f32x4 acc[2];
    acc[0] = (f32x4){0.f, 0.f, 0.f, 0.f};
    acc[1] = (f32x4){0.f, 0.f, 0.f, 0.f};

    for (int ch = 0; ch < nchunks; ++ch) {
        const int buf = ch & 1;
        float4 pre[2];
        if (ch + 1 < nchunks) {
            #pragma unroll
            for (int u = 0; u < 2; ++u) {
                int c = tid + u * 256;
                int row = c >> 4, col = (c & 15) * 4;
                pre[u] = *(const float4*)&A[(size_t)(m0 + row) * CDIM + (ch + 1) * 64 + col];
            }
        }
        #pragma unroll
        for (int kt = 0; kt < 2; ++kt) {
            half8 bb = Bc[(size_t)((ch * 2 + kt) * 48 + nsgBase) * 64 + lane];
            #pragma unroll
            for (int ms = 0; ms < 2; ++ms) {
                float f[8];
                *(float4*)&f[0] = *(const float4*)&As[buf][ms * 16 + lane15][kt * 32 + quad * 8];
                *(float4*)&f[4] = *(const float4*)&As[buf][ms * 16 + lane15][kt * 32 + quad * 8 + 4];
                half8 ah, al;
                split8_f16(f, ah, al);
                acc[ms] = __builtin_amdgcn_mfma_f32_16x16x32_f16(ah, bb, acc[ms], 0, 0, 0);
                acc[ms] = __builtin_amdgcn_mfma_f32_16x16x32_f16(al, bb, acc[ms], 0, 0, 0);
            }
        }
        if (ch + 1 < nchunks) {
            #pragma unroll
            for (int u = 0; u < 2; ++u) {
                int c = tid + u * 256;
                int row = c >> 4, col = (c & 15) * 4;
                *(float4*)&As[1 - buf][row][col] = pre[u];
            }
        }
        __syncthreads();
    }

    const int coln = bx * 64 + wave * 16 + lane15;
    #pragma unroll
    for (int ms = 0; ms < 2; ++ms)
        #pragma unroll
        for (int r = 0; r < 4; ++r) {
            int row = m0 + ms * 16 + quad * 4 + r;
            float v = acc[ms][r];
            if (act) v = elu1(v);
            Cmat[(size_t)row * CDIM + coln] = v;
        }
}

// ---------- prep: map W -> f16 fragment-major blob (4096x128) ----------
__global__ __launch_bounds__(256) void prep_w(
    const float* __restrict__ Wks, const float* __restrict__ Wvs,
    _Float16* __restrict__ Wblob)
{
    const int idx = blockIdx.x * 256 + threadIdx.x;
    const int kk = idx >> 7, n = idx & 127;
    float f = (n < 64) ? Wks[(size_t)kk * 64 + n] : Wvs[(size_t)kk * 64 + (n - 64)];
    const int i = kk >> 6, kl = kk & 63;
    const int ks = kl >> 5, quad = (kl >> 3) & 3, j = kl & 7;
    const int nsg = n >> 4, lane15 = n & 15;
    const int lane = quad * 16 + lane15;
    const size_t off = ((size_t)(((i * 2 + ks) * 8 + nsg)) * 64 + lane) * 8 + j;
    Wblob[off] = (_Float16)f;
}

// ---------- MFMA mapped features v5: wave = nsg-pair x all 32 pos (no B duplication),
// packed-f16 A-generation (v_pk_mul_f16), 4-stage pipelined B/K ----------
__global__ __launch_bounds__(256, 3) void map_f16(
    const float* __restrict__ kbuf, const float* __restrict__ vbuf,
    const _Float16* __restrict__ Wblob,
    float* __restrict__ kkv, float* __restrict__ vvv)
{
    __shared__ float kS[32][68];

    const int tid = threadIdx.x;
    const int p0 = blockIdx.x * 32;
    const int wave = tid >> 6, lane = tid & 63;
    const int lane15 = lane & 15, quad = lane >> 4;
    // wave w owns output groups nsg {2w, 2w+1}; computes both position halves

    #pragma unroll
    for (int u = 0; u < 2; ++u) {
        int c = tid + u * 256;
        int row = c >> 4, col = (c & 15) * 4;
        *(float4*)&kS[row][col] = *(const float4*)&kbuf[(size_t)(p0 + row) * 64 + col];
    }

    // v in f16 (RTZ), both position halves: vrh[mh][ks]
    half8 vrh[2][2];
    #pragma unroll
    for (int mh = 0; mh < 2; ++mh) {
        const size_t pbase = (size_t)(p0 + mh * 16 + lane15) * 64;
        #pragma unroll
        for (int ks = 0; ks < 2; ++ks) {
            float f[8];
            *(float4*)&f[0] = *(const float4*)&vbuf[pbase + ks * 32 + quad * 8];
            *(float4*)&f[4] = *(const float4*)&vbuf[pbase + ks * 32 + quad * 8 + 4];
            union { fp16x2 h2[4]; half8 h8; } u;
            #pragma unroll
            for (int jp = 0; jp < 4; ++jp)
                u.h2[jp] = __builtin_amdgcn_cvt_pkrtz(f[2 * jp], f[2 * jp + 1]);
            vrh[mh][ks] = u.h8;
        }
    }
    __syncthreads();

    const half8* __restrict__ Wc = (const half8*)Wblob;

    f32x4 acc[2][2];   // [mh][nsl]
    #pragma unroll
    for (int mh = 0; mh < 2; ++mh)
        #pragma unroll
        for (int nsl = 0; nsl < 2; ++nsl)
            acc[mh][nsl] = (f32x4){0.f, 0.f, 0.f, 0.f};

    half8 b0[2], b1[2], b2[2], b3[2];
    float2 k0, k1, k2, k3;

    auto loadB = [&](half8* b, int s) {
        b[0] = Wc[(size_t)(s * 8 + 2 * wave) * 64 + lane];
        b[1] = Wc[(size_t)(s * 8 + 2 * wave + 1) * 64 + lane];
    };
    auto loadK = [&](float2& kf, int s) {
        kf.x = kS[lane15][s >> 1];
        kf.y = kS[16 + lane15][s >> 1];
    };
    auto compute = [&](const half8* b, float2 kf, int s) {
        const int ks = s & 1;
        #pragma unroll
        for (int mh = 0; mh < 2; ++mh) {
            float kv = mh ? kf.y : kf.x;
            fp16x2 k2 = __builtin_amdgcn_cvt_pkrtz(kv, kv);
            union { fp16x2 h2[4]; half8 h8; } kb;
            kb.h2[0] = k2; kb.h2[1] = k2; kb.h2[2] = k2; kb.h2[3] = k2;
            half8 a = kb.h8 * vrh[mh][ks];   // 4x v_pk_mul_f16
            acc[mh][0] = __builtin_amdgcn_mfma_f32_16x16x32_f16(a, b[0], acc[mh][0], 0, 0, 0);
            acc[mh][1] = __builtin_amdgcn_mfma_f32_16x16x32_f16(a, b[1], acc[mh][1], 0, 0, 0);
        }
    };

    loadB(b0, 0); loadB(b1, 1); loadB(b2, 2); loadB(b3, 3);
    loadK(k0, 0); loadK(k1, 1); loadK(k2, 2); loadK(k3, 3);
    for (int s = 0; s < 128; s += 4) {
        const bool more = (s + 4) < 128;
        compute(b0, k0, s);
        compute(b1, k1, s + 1);
        if (more) { loadB(b0, s + 4); loadK(k0, s + 4); loadB(b1, s + 5); loadK(k1, s + 5); }
        compute(b2, k2, s + 2);
        compute(b3, k3, s + 3);
        if (more) { loadB(b2, s + 6); loadK(k2, s + 6); loadB(b3, s + 7); loadK(k3, s + 7); }
    }

    // epilogue: C/D layout col=lane15, row=quad*4+r; n128 = (2w+nsl)*16+lane15
    #pragma unroll
    for (int mh = 0; mh < 2; ++mh)
        #pragma unroll
        for (int nsl = 0; nsl < 2; ++nsl) {
            int n128 = (2 * wave + nsl) * 16 + lane15;
            float* dst = (n128 < 64) ? kkv : vvv;
            int col = n128 & 63;
            #pragma unroll
            for (int r = 0; r < 4; ++r) {
                int p = p0 + mh * 16 + quad * 4 + r;
                dst[(size_t)p * 64 + col] = acc[mh][nsl][r];
            }
        }
}

// ---------- set features (levels 2..7) + fused tail cumsum ----------
__global__ __launch_bounds__(256) void set_lower(
    const float* __restrict__ kkv, const float* __restrict__ vvv,
    const float* __restrict__ bks, const float* __restrict__ bvs,
    float* __restrict__ Kset, float* __restrict__ Vset,
    float* __restrict__ scrK, float* __restrict__ scrV,
    float* __restrict__ Kt, float* __restrict__ Vt)
{
    __shared__ float curK[63][64];
    __shared__ float curV[63][64];
    const int tid = threadIdx.x;
    const int col = tid & 63, grp = tid >> 6;
    const int h = blockIdx.x % NHEAD;
    const int c = blockIdx.x / NHEAD;
    const int t0 = c * 128;
    const float bk = bks[col], bv = bvs[col];

    for (int j = grp; j < 32; j += 4) {
        const size_t rbase = (size_t)(t0 + j * 4) * CDIM + h * 64 + col;
        const float* pk = kkv + rbase;
        const float* pv = vvv + rbase;
        float* ptK = Kt + rbase;
        float* ptV = Vt + rbase;
        float sk = bk, sv = bv;
        #pragma unroll
        for (int u = 0; u < 4; ++u) {
            sk += pk[(size_t)u * CDIM];
            sv += pv[(size_t)u * CDIM];
            ptK[(size_t)u * CDIM] = sk;
            ptV[(size_t)u * CDIM] = sv;
        }
        curK[j][col] = sk - bk; curV[j][col] = sv - bv;
        size_t o = ((size_t)(c * 32 + j) * NHEAD + h) * 64 + col;
        Kset[o] = sk; Vset[o] = sv;
    }
    __syncthreads();

    const int LBASE[6] = {0, 32, 48, 56, 60, 62};
    const int GBASE[6] = {0, 512, 768, 896, 960, 992};
    #pragma unroll
    for (int li = 1; li < 6; ++li) {
        const int ns = 32 >> li;
        for (int j = grp; j < ns; j += 4) {
            float sk = curK[LBASE[li - 1] + 2 * j][col] + curK[LBASE[li - 1] + 2 * j + 1][col];
            float sv = curV[LBASE[li - 1] + 2 * j][col] + curV[LBASE[li - 1] + 2 * j + 1][col];
            curK[LBASE[li] + j][col] = sk; curV[LBASE[li] + j][col] = sv;
            size_t o = ((size_t)(GBASE[li] + c * ns + j) * NHEAD + h) * 64 + col;
            Kset[o] = sk + bk; Vset[o] = sv + bv;
        }
        __syncthreads();
    }

    if (grp == 0) {
        scrK[((size_t)h * 16 + c) * 64 + col] = curK[62][col];
        scrV[((size_t)h * 16 + c) * 64 + col] = curV[62][col];
    }
}

__global__ __launch_bounds__(256) void set_upper(
    const float* __restrict__ scrK, const float* __restrict__ scrV,
    const float* __restrict__ bks, const float* __restrict__ bvs,
    float* __restrict__ Kset, float* __restrict__ Vset)
{
    __shared__ float cK[15][64], cV[15][64];
    const int h = blockIdx.x;
    const int tid = threadIdx.x, col = tid & 63, grp = tid >> 6;
    const float bk = bks[col], bv = bvs[col];

    for (int j = grp; j < 8; j += 4) {
        float sk = scrK[((size_t)h * 16 + 2 * j) * 64 + col] + scrK[((size_t)h * 16 + 2 * j + 1) * 64 + col];
        float sv = scrV[((size_t)h * 16 + 2 * j) * 64 + col] + scrV[((size_t)h * 16 + 2 * j + 1) * 64 + col];
        cK[j][col] = sk; cV[j][col] = sv;
        size_t o = ((size_t)(1008 + j) * NHEAD + h) * 64 + col;
        Kset[o] = sk + bk; Vset[o] = sv + bv;
    }
    __syncthreads();
    const int LB[4] = {0, 8, 12, 14};
    const int GB[4] = {1008, 1016, 1020, 1022};
    #pragma unroll
    for (int li = 1; li < 4; ++li) {
        const int ns = 8 >> li;
        for (int j = grp; j < ns; j += 4) {
            float sk = cK[LB[li - 1] + 2 * j][col] + cK[LB[li - 1] + 2 * j + 1][col];
            float sv = cV[LB[li - 1] + 2 * j][col] + cV[LB[li - 1] + 2 * j + 1][col];
            cK[LB[li] + j][col] = sk; cV[LB[li] + j][col] = sv;
            size_t o = ((size_t)(GB[li] + j) * NHEAD + h) * 64 + col;
            Kset[o] = sk + bk; Vset[o] = sv + bv;
        }
        __syncthreads();
    }
}

// ---------- MFMA flash attention ----------
__global__ __launch_bounds__(256, 3) void attn_mfma(
    const float* __restrict__ qbuf, const float* __restrict__ Kset,
    const float* __restrict__ Vset, const float* __restrict__ Ktail,
    const float* __restrict__ Vtail, float* __restrict__ attout)
{
    __shared__ float vS[64][66];
    __shared__ float sS[32][68];
    __shared__ float mrow[32], lrow[32], arow[32];
    __shared__ float red[32][8];
    __shared__ int   sid[64], send[64];

    const int tid = threadIdx.x;
    const int b   = 63 - (blockIdx.x / NHEAD);
    const int h   = blockIdx.x % NHEAD;
    const int T0  = b * 32;
    const int wave = tid >> 6, lane = tid & 63;
    const int lane15 = lane & 15, quad = lane >> 4;

    const int Tend = T0 + 32;
    const int LOFF[10] = {0, 512, 768, 896, 960, 992, 1008, 1016, 1020, 1022};
    int pfx[10], Vtot = 0;
    #pragma unroll
    for (int li = 0; li < 10; ++li) { pfx[li] = Vtot; Vtot += Tend >> (li + 2); }

    short8 Qhi[2][2], Qlo[2][2];
    #pragma unroll
    for (int ms = 0; ms < 2; ++ms)
        #pragma unroll
        for (int kt = 0; kt < 2; ++kt) {
            const float* qp = qbuf + ((size_t)(T0 + ms * 16 + lane15) * NHEAD + h) * 64 + kt * 32 + quad * 8;
            float f[8];
            *(float4*)&f[0] = *(const float4*)qp;
            *(float4*)&f[4] = *(const float4*)(qp + 4);
            split8_bf16(f, Qhi[ms][kt], Qlo[ms][kt]);
        }

    if (tid < 32) { mrow[tid] = -1e30f; lrow[tid] = 0.f; }

    f32x4 oacc[2];
    oacc[0] = (f32x4){0.f, 0.f, 0.f, 0.f};
    oacc[1] = (f32x4){0.f, 0.f, 0.f, 0.f};

    const int ntiles = (Vtot + 63) >> 6;
    const int row = tid >> 3, part = tid & 7;

    for (int tile = 0; tile < ntiles; ++tile) {
        __syncthreads();

        if (tid < 64) {
            int j = tile * 64 + tid;
            int s_ = 0, e_ = 0x7fffffff;
            if (j < Vtot) {
                int li = 0;
                #pragma unroll
                for (int u = 1; u < 10; ++u) if (j >= pfx[u]) li = u;
                int idx = j - pfx[li];
                s_ = LOFF[li] + idx;
                e_ = (idx + 1) << (li + 2);
            }
            sid[tid] = s_; send[tid] = e_;
        }
        __syncthreads();

        #pragma unroll
        for (int i = 0; i < 4; ++i) {
            int s  = (tid >> 4) + 16 * i;
            int d4 = tid & 15;
            *(float4*)&vS[s][d4 * 4] =
                *(const float4*)&Vset[((size_t)sid[s] * NHEAD + h) * 64 + d4 * 4];
        }

        short8 Khi[2], Klo[2];
        {
            const int sK = sid[wave * 16 + lane15];
            const float* kp = Kset + ((size_t)sK * NHEAD + h) * 64 + quad * 8;
            #pragma unroll
            for (int kt = 0; kt < 2; ++kt) {
                float f[8];
                *(float4*)&f[0] = *(const float4*)(kp + kt * 32);
                *(float4*)&f[4] = *(const float4*)(kp + kt * 32 + 4);
                split8_bf16(f, Khi[kt], Klo[kt]);
            }
        }

        f32x4 lacc[2];
        lacc[0] = (f32x4){0.f, 0.f, 0.f, 0.f};
        lacc[1] = (f32x4){0.f, 0.f, 0.f, 0.f};
        #pragma unroll
        for (int kt = 0; kt < 2; ++kt)
            #pragma unroll
            for (int ms = 0; ms < 2; ++ms) {
                lacc[ms] = __builtin_amdgcn_mfma_f32_16x16x32_bf16(Qhi[ms][kt], Khi[kt], lacc[ms], 0, 0, 0);
                lacc[ms] = __builtin_amdgcn_mfma_f32_16x16x32_bf16(Qlo[ms][kt], Khi[kt], lacc[ms], 0, 0, 0);
                lacc[ms] = __builtin_amdgcn_mfma_f32_16x16x32_bf16(Qhi[ms][kt], Klo[kt], lacc[ms], 0, 0, 0);
            }

        {
            const int sendv = send[wave * 16 + lane15];
            #pragma unroll
            for (int ms = 0; ms < 2; ++ms)
                #pragma unroll
                for (int r = 0; r < 4; ++r) {
                    int qrow = ms * 16 + quad * 4 + r;
                    bool ok = (T0 + qrow + 1) >= sendv;
                    sS[qrow][wave * 16 + lane15] = ok ? lacc[ms][r] * 0.125f : -1e30f;
                }
        }
        __syncthreads();

        float4* sr = (float4*)&sS[row][0];
        {
            float4 a = sr[part * 2], c4 = sr[part * 2 + 1];
            float mx = fmaxf(fmaxf(fmaxf(a.x, a.y), fmaxf(a.z, a.w)),
                             fmaxf(fmaxf(c4.x, c4.y), fmaxf(c4.z, c4.w)));
            red[row][part] = mx;
        }
        __syncthreads();
        if (tid < 32) {
            float rmax = red[tid][0];
            #pragma unroll
            for (int u = 1; u < 8; ++u) rmax = fmaxf(rmax, red[tid][u]);
            float mold = mrow[tid];
            float mnew = fmaxf(mold, rmax);
            arow[tid] = __expf(mold - mnew);
            mrow[tid] = mnew;
        }
        __syncthreads();

        {
            const float mn = mrow[row];
            float4 a = sr[part * 2], c4 = sr[part * 2 + 1];
            a.x = a.x > -1e29f ? __expf(a.x - mn) : 0.f;
            a.y = a.y > -1e29f ? __expf(a.y - mn) : 0.f;
            a.z = a.z > -1e29f ? __expf(a.z - mn) : 0.f;
            a.w = a.w > -1e29f ? __expf(a.w - mn) : 0.f;
            c4.x = c4.x > -1e29f ? __expf(c4.x - mn) : 0.f;
            c4.y = c4.y > -1e29f ? __expf(c4.y - mn) : 0.f;
            c4.z = c4.z > -1e29f ? __expf(c4.z - mn) : 0.f;
            c4.w = c4.w > -1e29f ? __expf(c4.w - mn) : 0.f;
            sr[part * 2] = a; sr[part * 2 + 1] = c4;
            red[row][part] = (a.x + a.y + a.z + a.w) + (c4.x + c4.y + c4.z + c4.w);
        }
        __syncthreads();
        if (tid < 32) {
            float t = 0.f;
            #pragma unroll
            for (int u = 0; u < 8; ++u) t += red[tid][u];
            lrow[tid] = arow[tid] * lrow[tid] + t;
        }

        #pragma unroll
        for (int ms = 0; ms < 2; ++ms)
            #pragma unroll
            for (int r = 0; r < 4; ++r)
                oacc[ms][r] *= arow[ms * 16 + quad * 4 + r];
        // (no barrier needed: sS/vS visibility guaranteed by the pass-2 reduction barrier)

        #pragma unroll
        for (int kt = 0; kt < 2; ++kt) {
            short8 Pf[2];
            #pragma unroll
            for (int ms = 0; ms < 2; ++ms) {
                const float* pp = &sS[ms * 16 + lane15][kt * 32 + quad * 8];
                float f[8];
                *(float4*)&f[0] = *(const float4*)pp;
                *(float4*)&f[4] = *(const float4*)(pp + 4);
                unsigned w[4];
                #pragma unroll
                for (int p = 0; p < 4; ++p) w[p] = pack2_bf16_rne(f[2 * p], f[2 * p + 1]);
                Pf[ms] = mk_short8(w);
            }
            unsigned vw[4];
            #pragma unroll
            for (int jp = 0; jp < 4; ++jp) {
                float a = vS[kt * 32 + quad * 8 + 2 * jp][wave * 16 + lane15];
                float bb = vS[kt * 32 + quad * 8 + 2 * jp + 1][wave * 16 + lane15];
                vw[jp] = pack2_bf16_rne(a, bb);
            }
            short8 Vf = mk_short8(vw);
            #pragma unroll
            for (int ms = 0; ms < 2; ++ms)
                oacc[ms] = __builtin_amdgcn_mfma_f32_16x16x32_bf16(Pf[ms], Vf, oacc[ms], 0, 0, 0);
        }
    }

    __syncthreads();

    {
        const float* qr = qbuf  + ((size_t)(T0 + row) * NHEAD + h) * 64;
        const float* kr = Ktail + ((size_t)(T0 + row) * NHEAD + h) * 64;
        float dp = 0.f;
        for (int d = part; d < 64; d += 8) dp += qr[d] * kr[d];
        red[row][part] = dp;
    }
    __syncthreads();
    if (tid < 32) {
        float tl = 0.f;
        #pragma unroll
        for (int u = 0; u < 8; ++u) tl += red[tid][u];
        tl *= 0.125f;
        float mold = mrow[tid];
        float mf = fmaxf(mold, tl);
        float al = __expf(mold - mf);
        float pt = __expf(tl - mf);
        float lf = al * lrow[tid] + pt;
        arow[tid] = al;
        lrow[tid] = pt / lf;
        mrow[tid] = 1.f / lf;
    }
    __syncthreads();

    #pragma unroll
    for (int ms = 0; ms < 2; ++ms)
        #pragma unroll
        for (int r = 0; r < 4; ++r) {
            int qrow = ms * 16 + quad * 4 + r;
            int col = wave * 16 + lane15;
            float al_inv = arow[qrow] * mrow[qrow];
            float ptinv = lrow[qrow];
            size_t base = ((size_t)(T0 + qrow) * NHEAD + h) * 64 + col;
            attout[base] = oacc[ms][r] * al_inv + ptinv * Vtail[base];
        }
}

extern "C" void kernel_launch(void* const* d_in, const int* in_sizes, int n_in,
                              void* d_out, int out_size, void* d_ws, size_t ws_size,
                              hipStream_t stream)
{
    const float* x   = (const float*)d_in[0];
    const float* Wq  = (const float*)d_in[1];
    const float* Wk  = (const float*)d_in[2];
    const float* Wv  = (const float*)d_in[3];
    const float* Wks = (const float*)d_in[4];
    const float* bks = (const float*)d_in[5];
    const float* Wvs = (const float*)d_in[6];
    const float* bvs = (const float*)d_in[7];
    const float* Wc  = (const float*)d_in[8];
    const float* bc  = (const float*)d_in[9];
    float* out = (float*)d_out;

    float* ws = (float*)d_ws;
    const size_t TC = (size_t)TLEN * CDIM;
    float* q      = ws;
    float* k      = q + TC;
    float* v      = k + TC;
    float* kkv    = v + TC;
    float* vvv    = kkv + TC;
    float* Kt     = vvv + TC;
    float* Vt     = Kt + TC;
    float* Kset   = Vt + TC;
    float* Vset   = Kset + (size_t)NSETS * CDIM;
    float* attout = Vset + (size_t)NSETS * CDIM;
    _Float16* WblobMap = (_Float16*)attout;
    _Float16* blobQKV  = (_Float16*)(attout + 262144);
    float* scrK = attout + 1146880;
    float* scrV = scrK + 12 * 16 * 64;
    _Float16* blobC = (_Float16*)k;   // k dead after map_f16

    prep_w768x3<<<3 * 2304, 256, 0, stream>>>(Wq, Wk, Wv, blobQKV);
    prep_w<<<(4096 * 128) / 256, 256, 0, stream>>>(Wks, Wvs, WblobMap);

    gemm_qkv<<<dim3(36, 64), 256, 0, stream>>>(x, blobQKV, q);

    map_f16<<<(TLEN * NHEAD) / 32, 256, 0, stream>>>(k, v, WblobMap, kkv, vvv);

    prep_w768<<<2304, 256, 0, stream>>>(Wc, blobC);

    set_lower<<<16 * NHEAD, 256, 0, stream>>>(kkv, vvv, bks, bvs, Kset, Vset, scrK, scrV, Kt, Vt);
    set_upper<<<NHEAD, 256, 0, stream>>>(scrK, scrV, bks, bvs, Kset, Vset);

    attn_mfma<<<(TLEN / 32) * NHEAD, 256, 0, stream>>>(q, Kset, Vset, Kt, Vt, attout);

    gemm_mfma<0, 1><<<dim3(12, 64), 256, 0, stream>>>(attout, blobC, bc, out, TLEN, CDIM, CDIM);
}

// Round 13
// 236.435 us; speedup vs baseline: 1.1985x; 1.0899x over previous
//
#include <hip/hip_runtime.h>
#include <cstdint>

#define NHEAD 12
#define TLEN 2048
#define CDIM 768
#define NSETS 1023   // 512+256+128+64+32+16+8+4+2+1

typedef __attribute__((ext_vector_type(8))) _Float16 half8;
typedef __attribute__((ext_vector_type(2))) __fp16 fp16x2;
typedef __attribute__((ext_vector_type(8))) short short8;   // 8 bf16
typedef __attribute__((ext_vector_type(4))) float f32x4;

__device__ __forceinline__ float elu1(float x) { return x > 0.f ? x + 1.f : __expf(x); }

__device__ __forceinline__ unsigned pack2_bf16_trunc(float a, float b) {
    unsigned ua = __float_as_uint(a), ub = __float_as_uint(b);
    return __builtin_amdgcn_perm(ub, ua, 0x07060302);
}
__device__ __forceinline__ unsigned pack2_bf16_rne(float a, float b) {
    unsigned ua = __float_as_uint(a), ub = __float_as_uint(b);
    ua = ua + 0x7fff + ((ua >> 16) & 1);
    ub = ub + 0x7fff + ((ub >> 16) & 1);
    return (ub & 0xffff0000u) | (ua >> 16);
}
__device__ __forceinline__ short8 mk_short8(const unsigned* u) {
    union { unsigned w[4]; short8 s; } x;
    x.w[0] = u[0]; x.w[1] = u[1]; x.w[2] = u[2]; x.w[3] = u[3];
    return x.s;
}
__device__ __forceinline__ void split8_bf16(const float* f, short8& hi, short8& lo) {
    unsigned hp[4], lp[4];
    #pragma unroll
    for (int p = 0; p < 4; ++p) {
        float a = f[2 * p], b = f[2 * p + 1];
        unsigned ua = __float_as_uint(a), ub = __float_as_uint(b);
        hp[p] = __builtin_amdgcn_perm(ub, ua, 0x07060302);
        float ra = a - __uint_as_float(ua & 0xffff0000u);
        float rb = b - __uint_as_float(ub & 0xffff0000u);
        lp[p] = pack2_bf16_trunc(ra, rb);
    }
    hi = mk_short8(hp); lo = mk_short8(lp);
}
__device__ __forceinline__ void split8_f16(const float* f, half8& hi, half8& lo) {
    union { fp16x2 h2[4]; half8 h8; } uh, ul;
    #pragma unroll
    for (int jp = 0; jp < 4; ++jp) {
        float a = f[2 * jp], b = f[2 * jp + 1];
        fp16x2 hh = __builtin_amdgcn_cvt_pkrtz(a, b);
        uh.h2[jp] = hh;
        ul.h2[jp] = __builtin_amdgcn_cvt_pkrtz(a - (float)hh[0], b - (float)hh[1]);
    }
    hi = uh.h8; lo = ul.h8;
}

// ---------- prep: 768x768 W -> f16 fragment-major blob ----------
__global__ __launch_bounds__(256) void prep_w768(
    const float* __restrict__ W, _Float16* __restrict__ blob)
{
    const int idx = blockIdx.x * 256 + threadIdx.x;
    const int k = idx / 768, n = idx % 768;
    const int i = k >> 5, kl = k & 31;
    const int quad = kl >> 3, j = kl & 7;
    const int nsg = n >> 4, lane15 = n & 15;
    const int lane = quad * 16 + lane15;
    blob[((size_t)(i * 48 + nsg) * 64 + lane) * 8 + j] = (_Float16)W[idx];
}

__global__ __launch_bounds__(256) void prep_w768x3(
    const float* __restrict__ Wq, const float* __restrict__ Wk,
    const float* __restrict__ Wv, _Float16* __restrict__ blobs)
{
    const int g = blockIdx.x;
    const int sel = g / 2304;
    const float* W = sel == 0 ? Wq : (sel == 1 ? Wk : Wv);
    _Float16* blob = blobs + (size_t)sel * 589824;
    const int idx = (g % 2304) * 256 + threadIdx.x;
    const int k = idx / 768, n = idx % 768;
    const int i = k >> 5, kl = k & 31;
    const int quad = kl >> 3, j = kl & 7;
    const int nsg = n >> 4, lane15 = n & 15;
    const int lane = quad * 16 + lane15;
    blob[((size_t)(i * 48 + nsg) * 64 + lane) * 8 + j] = (_Float16)W[idx];
}

// ---------- MFMA GEMM core (final projection) ----------
template<int ACT, int BIAS>
__global__ __launch_bounds__(256, 3) void gemm_mfma(
    const float* __restrict__ A, const _Float16* __restrict__ Bblob,
    const float* __restrict__ bias, float* __restrict__ Cmat,
    int M, int N, int K)
{
    __shared__ float As[2][32][68];
    const int tid = threadIdx.x;
    const int wave = tid >> 6, lane = tid & 63;
    const int lane15 = lane & 15, quad = lane >> 4;
    const int m0 = blockIdx.y * 32;
    const int nsgBase = blockIdx.x * 4 + wave;
    const int nchunks = K >> 6;

    const half8* __restrict__ Bc = (const half8*)Bblob;

    #pragma unroll
    for (int u = 0; u < 2; ++u) {
        int c = tid + u * 256;
        int row = c >> 4, col = (c & 15) * 4;
        *(float4*)&As[0][row][col] = *(const float4*)&A[(size_t)(m0 + row) * K + col];
    }
    __syncthreads();

    f32x4 acc[2];
    acc[0] = (f32x4){0.f, 0.f, 0.f, 0.f};
    acc[1] = (f32x4){0.f, 0.f, 0.f, 0.f};

    for (int ch = 0; ch < nchunks; ++ch) {
        const int buf = ch & 1;
        float4 pre[2];
        if (ch + 1 < nchunks) {
            #pragma unroll
            for (int u = 0; u < 2; ++u) {
                int c = tid + u * 256;
                int row = c >> 4, col = (c & 15) * 4;
                pre[u] = *(const float4*)&A[(size_t)(m0 + row) * K + (ch + 1) * 64 + col];
            }
        }
        #pragma unroll
        for (int kt = 0; kt < 2; ++kt) {
            half8 bb = Bc[(size_t)((ch * 2 + kt) * 48 + nsgBase) * 64 + lane];
            #pragma unroll
            for (int ms = 0; ms < 2; ++ms) {
                float f[8];
                *(float4*)&f[0] = *(const float4*)&As[buf][ms * 16 + lane15][kt * 32 + quad * 8];
                *(float4*)&f[4] = *(const float4*)&As[buf][ms * 16 + lane15][kt * 32 + quad * 8 + 4];
                half8 ah, al;
                split8_f16(f, ah, al);
                acc[ms] = __builtin_amdgcn_mfma_f32_16x16x32_f16(ah, bb, acc[ms], 0, 0, 0);
                acc[ms] = __builtin_amdgcn_mfma_f32_16x16x32_f16(al, bb, acc[ms], 0, 0, 0);
            }
        }
        if (ch + 1 < nchunks) {
            #pragma unroll
            for (int u = 0; u < 2; ++u) {
                int c = tid + u * 256;
                int row = c >> 4, col = (c & 15) * 4;
                *(float4*)&As[1 - buf][row][col] = pre[u];
            }
        }
        __syncthreads();
    }

    const int coln = blockIdx.x * 64 + wave * 16 + lane15;
    #pragma unroll
    for (int ms = 0; ms < 2; ++ms)
        #pragma unroll
        for (int r = 0; r < 4; ++r) {
            int row = m0 + ms * 16 + quad * 4 + r;
            float v = acc[ms][r];
            if (BIAS) v += bias[coln];
            if (ACT) v = elu1(v);
            Cmat[(size_t)row * N + coln] = v;
        }
}

// ---------- fused QKV projection ----------
__global__ __launch_bounds__(256, 3) void gemm_qkv(
    const float* __restrict__ A, const _Float16* __restrict__ blobs,
    float* __restrict__ outbase)
{
    __shared__ float As[2][32][68];
    const int which = blockIdx.x / 12;
    const int bx = blockIdx.x % 12;
    const _Float16* Bblob = blobs + (size_t)which * 589824;
    float* Cmat = outbase + (size_t)which * ((size_t)TLEN * CDIM);
    const bool act = which < 2;

    const int tid = threadIdx.x;
    const int wave = tid >> 6, lane = tid & 63;
    const int lane15 = lane & 15, quad = lane >> 4;
    const int m0 = blockIdx.y * 32;
    const int nsgBase = bx * 4 + wave;
    const int nchunks = CDIM >> 6;

    const half8* __restrict__ Bc = (const half8*)Bblob;

    #pragma unroll
    for (int u = 0; u < 2; ++u) {
        int c = tid + u * 256;
        int row = c >> 4, col = (c & 15) * 4;
        *(float4*)&As[0][row][col] = *(const float4*)&A[(size_t)(m0 + row) * CDIM + col];
    }
    __syncthreads();

    f32x4 acc[2];
    acc[0] = (f32x4){0.f, 0.f, 0.f, 0.f};
    acc[1] = (f32x4){0.f, 0.f, 0.f, 0.f};

    for (int ch = 0; ch < nchunks; ++ch) {
        const int buf = ch & 1;
        float4 pre[2];
        if (ch + 1 < nchunks) {
            #pragma unroll
            for (int u = 0; u < 2; ++u) {
                int c = tid + u * 256;
                int row = c >> 4, col = (c & 15) * 4;
                pre[u] = *(const float4*)&A[(size_t)(m0 + row) * CDIM + (ch + 1) * 64 + col];
            }
        }
        #pragma unroll
        for (int kt = 0; kt < 2; ++kt) {
            half8 bb = Bc[(size_t)((ch * 2 + kt) * 48 + nsgBase) * 64 + lane];
            #pragma unroll
            for (int ms = 0; ms < 2; ++ms) {
                float f[8];
                *(float4*)&f[0] = *(const float4*)&As[buf][ms * 16 + lane15][kt * 32 + quad * 8];
                *(float4*)&f[4] = *(const float4*)&As[buf][ms * 16 + lane15][kt * 32 + quad * 8 + 4];
                half8 ah, al;
                split8_f16(f, ah, al);
                acc[ms] = __builtin_amdgcn_mfma_f32_16x16x32_f16(ah, bb, acc[ms], 0, 0, 0);
                acc[ms] = __builtin_amdgcn_mfma_f32_16x16x32_f16(al, bb, acc[ms], 0, 0, 0);
            }
        }
        if (ch + 1 < nchunks) {
            #pragma unroll
            for (int u = 0; u < 2; ++u) {
                int c = tid + u * 256;
                int row = c >> 4, col = (c & 15) * 4;
                *(float4*)&As[1 - buf][row][col] = pre[u];
            }
        }
        __syncthreads();
    }

    const int coln = bx * 64 + wave * 16 + lane15;
    #pragma unroll
    for (int ms = 0; ms < 2; ++ms)
        #pragma unroll
        for (int r = 0; r < 4; ++r) {
            int row = m0 + ms * 16 + quad * 4 + r;
            float v = acc[ms][r];
            if (act) v = elu1(v);
            Cmat[(size_t)row * CDIM + coln] = v;
        }
}

// ---------- prep: map W -> f16 fragment-major blob (4096x128) ----------
__global__ __launch_bounds__(256) void prep_w(
    const float* __restrict__ Wks, const float* __restrict__ Wvs,
    _Float16* __restrict__ Wblob)
{
    const int idx = blockIdx.x * 256 + threadIdx.x;
    const int kk = idx >> 7, n = idx & 127;
    float f = (n < 64) ? Wks[(size_t)kk * 64 + n] : Wvs[(size_t)kk * 64 + (n - 64)];
    const int i = kk >> 6, kl = kk & 63;
    const int ks = kl >> 5, quad = (kl >> 3) & 3, j = kl & 7;
    const int nsg = n >> 4, lane15 = n & 15;
    const int lane = quad * 16 + lane15;
    const size_t off = ((size_t)(((i * 2 + ks) * 8 + nsg)) * 64 + lane) * 8 + j;
    Wblob[off] = (_Float16)f;
}

// ---------- MFMA mapped features v5 ----------
__global__ __launch_bounds__(256, 3) void map_f16(
    const float* __restrict__ kbuf, const float* __restrict__ vbuf,
    const _Float16* __restrict__ Wblob,
    float* __restrict__ kkv, float* __restrict__ vvv)
{
    __shared__ float kS[32][68];

    const int tid = threadIdx.x;
    const int p0 = blockIdx.x * 32;
    const int wave = tid >> 6, lane = tid & 63;
    const int lane15 = lane & 15, quad = lane >> 4;

    #pragma unroll
    for (int u = 0; u < 2; ++u) {
        int c = tid + u * 256;
        int row = c >> 4, col = (c & 15) * 4;
        *(float4*)&kS[row][col] = *(const float4*)&kbuf[(size_t)(p0 + row) * 64 + col];
    }

    half8 vrh[2][2];
    #pragma unroll
    for (int mh = 0; mh < 2; ++mh) {
        const size_t pbase = (size_t)(p0 + mh * 16 + lane15) * 64;
        #pragma unroll
        for (int ks = 0; ks < 2; ++ks) {
            float f[8];
            *(float4*)&f[0] = *(const float4*)&vbuf[pbase + ks * 32 + quad * 8];
            *(float4*)&f[4] = *(const float4*)&vbuf[pbase + ks * 32 + quad * 8 + 4];
            union { fp16x2 h2[4]; half8 h8; } u;
            #pragma unroll
            for (int jp = 0; jp < 4; ++jp)
                u.h2[jp] = __builtin_amdgcn_cvt_pkrtz(f[2 * jp], f[2 * jp + 1]);
            vrh[mh][ks] = u.h8;
        }
    }
    __syncthreads();

    const half8* __restrict__ Wc = (const half8*)Wblob;

    f32x4 acc[2][2];
    #pragma unroll
    for (int mh = 0; mh < 2; ++mh)
        #pragma unroll
        for (int nsl = 0; nsl < 2; ++nsl)
            acc[mh][nsl] = (f32x4){0.f, 0.f, 0.f, 0.f};

    half8 b0[2], b1[2], b2[2], b3[2];
    float2 k0, k1, k2, k3;

    auto loadB = [&](half8* b, int s) {
        b[0] = Wc[(size_t)(s * 8 + 2 * wave) * 64 + lane];
        b[1] = Wc[(size_t)(s * 8 + 2 * wave + 1) * 64 + lane];
    };
    auto loadK = [&](float2& kf, int s) {
        kf.x = kS[lane15][s >> 1];
        kf.y = kS[16 + lane15][s >> 1];
    };
    auto compute = [&](const half8* b, float2 kf, int s) {
        const int ks = s & 1;
        #pragma unroll
        for (int mh = 0; mh < 2; ++mh) {
            float kv = mh ? kf.y : kf.x;
            fp16x2 k2v = __builtin_amdgcn_cvt_pkrtz(kv, kv);
            union { fp16x2 h2[4]; half8 h8; } kb;
            kb.h2[0] = k2v; kb.h2[1] = k2v; kb.h2[2] = k2v; kb.h2[3] = k2v;
            half8 a = kb.h8 * vrh[mh][ks];
            acc[mh][0] = __builtin_amdgcn_mfma_f32_16x16x32_f16(a, b[0], acc[mh][0], 0, 0, 0);
            acc[mh][1] = __builtin_amdgcn_mfma_f32_16x16x32_f16(a, b[1], acc[mh][1], 0, 0, 0);
        }
    };

    loadB(b0, 0); loadB(b1, 1); loadB(b2, 2); loadB(b3, 3);
    loadK(k0, 0); loadK(k1, 1); loadK(k2, 2); loadK(k3, 3);
    for (int s = 0; s < 128; s += 4) {
        const bool more = (s + 4) < 128;
        compute(b0, k0, s);
        compute(b1, k1, s + 1);
        if (more) { loadB(b0, s + 4); loadK(k0, s + 4); loadB(b1, s + 5); loadK(k1, s + 5); }
        compute(b2, k2, s + 2);
        compute(b3, k3, s + 3);
        if (more) { loadB(b2, s + 6); loadK(k2, s + 6); loadB(b3, s + 7); loadK(k3, s + 7); }
    }

    #pragma unroll
    for (int mh = 0; mh < 2; ++mh)
        #pragma unroll
        for (int nsl = 0; nsl < 2; ++nsl) {
            int n128 = (2 * wave + nsl) * 16 + lane15;
            float* dst = (n128 < 64) ? kkv : vvv;
            int col = n128 & 63;
            #pragma unroll
            for (int r = 0; r < 4; ++r) {
                int p = p0 + mh * 16 + quad * 4 + r;
                dst[(size_t)p * 64 + col] = acc[mh][nsl][r];
            }
        }
}

// ---------- set features (levels 2..7) + fused tail cumsum ----------
__global__ __launch_bounds__(256) void set_lower(
    const float* __restrict__ kkv, const float* __restrict__ vvv,
    const float* __restrict__ bks, const float* __restrict__ bvs,
    float* __restrict__ Kset, float* __restrict__ Vset,
    float* __restrict__ scrK, float* __restrict__ scrV,
    float* __restrict__ Kt, float* __restrict__ Vt)
{
    __shared__ float curK[63][64];
    __shared__ float curV[63][64];
    const int tid = threadIdx.x;
    const int col = tid & 63, grp = tid >> 6;
    const int h = blockIdx.x % NHEAD;
    const int c = blockIdx.x / NHEAD;
    const int t0 = c * 128;
    const float bk = bks[col], bv = bvs[col];

    for (int j = grp; j < 32; j += 4) {
        const size_t rbase = (size_t)(t0 + j * 4) * CDIM + h * 64 + col;
        const float* pk = kkv + rbase;
        const float* pv = vvv + rbase;
        float* ptK = Kt + rbase;
        float* ptV = Vt + rbase;
        float sk = bk, sv = bv;
        #pragma unroll
        for (int u = 0; u < 4; ++u) {
            sk += pk[(size_t)u * CDIM];
            sv += pv[(size_t)u * CDIM];
            ptK[(size_t)u * CDIM] = sk;
            ptV[(size_t)u * CDIM] = sv;
        }
        curK[j][col] = sk - bk; curV[j][col] = sv - bv;
        size_t o = ((size_t)(c * 32 + j) * NHEAD + h) * 64 + col;
        Kset[o] = sk; Vset[o] = sv;
    }
    __syncthreads();

    const int LBASE[6] = {0, 32, 48, 56, 60, 62};
    const int GBASE[6] = {0, 512, 768, 896, 960, 992};
    #pragma unroll
    for (int li = 1; li < 6; ++li) {
        const int ns = 32 >> li;
        for (int j = grp; j < ns; j += 4) {
            float sk = curK[LBASE[li - 1] + 2 * j][col] + curK[LBASE[li - 1] + 2 * j + 1][col];
            float sv = curV[LBASE[li - 1] + 2 * j][col] + curV[LBASE[li - 1] + 2 * j + 1][col];
            curK[LBASE[li] + j][col] = sk; curV[LBASE[li] + j][col] = sv;
            size_t o = ((size_t)(GBASE[li] + c * ns + j) * NHEAD + h) * 64 + col;
            Kset[o] = sk + bk; Vset[o] = sv + bv;
        }
        __syncthreads();
    }

    if (grp == 0) {
        scrK[((size_t)h * 16 + c) * 64 + col] = curK[62][col];
        scrV[((size_t)h * 16 + c) * 64 + col] = curV[62][col];
    }
}

__global__ __launch_bounds__(256) void set_upper(
    const float* __restrict__ scrK, const float* __restrict__ scrV,
    const float* __restrict__ bks, const float* __restrict__ bvs,
    float* __restrict__ Kset, float* __restrict__ Vset)
{
    __shared__ float cK[15][64], cV[15][64];
    const int h = blockIdx.x;
    const int tid = threadIdx.x, col = tid & 63, grp = tid >> 6;
    const float bk = bks[col], bv = bvs[col];

    for (int j = grp; j < 8; j += 4) {
        float sk = scrK[((size_t)h * 16 + 2 * j) * 64 + col] + scrK[((size_t)h * 16 + 2 * j + 1) * 64 + col];
        float sv = scrV[((size_t)h * 16 + 2 * j) * 64 + col] + scrV[((size_t)h * 16 + 2 * j + 1) * 64 + col];
        cK[j][col] = sk; cV[j][col] = sv;
        size_t o = ((size_t)(1008 + j) * NHEAD + h) * 64 + col;
        Kset[o] = sk + bk; Vset[o] = sv + bv;
    }
    __syncthreads();
    const int LB[4] = {0, 8, 12, 14};
    const int GB[4] = {1008, 1016, 1020, 1022};
    #pragma unroll
    for (int li = 1; li < 4; ++li) {
        const int ns = 8 >> li;
        for (int j = grp; j < ns; j += 4) {
            float sk = cK[LB[li - 1] + 2 * j][col] + cK[LB[li - 1] + 2 * j + 1][col];
            float sv = cV[LB[li - 1] + 2 * j][col] + cV[LB[li - 1] + 2 * j + 1][col];
            cK[LB[li] + j][col] = sk; cV[LB[li] + j][col] = sv;
            size_t o = ((size_t)(GB[li] + j) * NHEAD + h) * 64 + col;
            Kset[o] = sk + bk; Vset[o] = sv + bv;
        }
        __syncthreads();
    }
}

// ---------- MFMA flash attention v2: pre-decoded sets, register softmax (shfl),
// pair-packed bf16 P/V in LDS (single b128 fragment reads), K/V global prefetch ----------
__global__ __launch_bounds__(256, 3) void attn_mfma(
    const float* __restrict__ qbuf, const float* __restrict__ Kset,
    const float* __restrict__ Vset, const float* __restrict__ Ktail,
    const float* __restrict__ Vtail, float* __restrict__ attout)
{
    __shared__ int   sidAll[1024], sendAll[1024];
    __shared__ float sS[32][68];           // raw masked logits (f32)
    __shared__ unsigned sP[32][40];        // P as bf16 pairs along k
    __shared__ unsigned vP[64][40];        // V^T as bf16 pairs along set: vP[dim][setpair]
    __shared__ float arowS[32];
    __shared__ float alS[32], ptS[32];

    const int tid = threadIdx.x;
    const int b   = 63 - (blockIdx.x / NHEAD);   // heavy blocks dispatched first
    const int h   = blockIdx.x % NHEAD;
    const int T0  = b * 32;
    const int wave = tid >> 6, lane = tid & 63;
    const int lane15 = lane & 15, quad = lane >> 4;

    const int Tend = T0 + 32;
    const int LOFF[10] = {0, 512, 768, 896, 960, 992, 1008, 1016, 1020, 1022};
    int pfx[10], Vtot = 0;
    #pragma unroll
    for (int li = 0; li < 10; ++li) { pfx[li] = Vtot; Vtot += Tend >> (li + 2); }
    const int ntiles = (Vtot + 63) >> 6;

    // decode all set slots once
    for (int j = tid; j < 1024; j += 256) {
        int s_ = 0, e_ = 0x7fffffff;
        if (j < Vtot) {
            int li = 0;
            #pragma unroll
            for (int u = 1; u < 10; ++u) if (j >= pfx[u]) li = u;
            int idx = j - pfx[li];
            s_ = LOFF[li] + idx;
            e_ = (idx + 1) << (li + 2);
        }
        sidAll[j] = s_; sendAll[j] = e_;
    }

    // Q A-fragments, exact bf16 hi/lo split (held all block)
    short8 Qhi[2][2], Qlo[2][2];
    #pragma unroll
    for (int ms = 0; ms < 2; ++ms)
        #pragma unroll
        for (int kt = 0; kt < 2; ++kt) {
            const float* qp = qbuf + ((size_t)(T0 + ms * 16 + lane15) * NHEAD + h) * 64 + kt * 32 + quad * 8;
            float f[8];
            *(float4*)&f[0] = *(const float4*)qp;
            *(float4*)&f[4] = *(const float4*)(qp + 4);
            split8_bf16(f, Qhi[ms][kt], Qlo[ms][kt]);
        }

    __syncthreads();   // sidAll/sendAll ready

    // per-thread softmax state (thread owns row tid>>3 across all tiles)
    const int row = tid >> 3, part = tid & 7;
    float mreg = -1e30f, lreg = 0.f;

    f32x4 oacc[2];
    oacc[0] = (f32x4){0.f, 0.f, 0.f, 0.f};
    oacc[1] = (f32x4){0.f, 0.f, 0.f, 0.f};

    // prefetch V (thread: setpair sp=tid>>3, dims (tid&7)*8..+7) and K (wave slice)
    float4 Vr[4];
    float4 Kr[4];
    const int sp = tid >> 3, dd = (tid & 7) * 8;
    auto prefV = [&](int tile) {
        int sa = sidAll[tile * 64 + 2 * sp];
        int sb = sidAll[tile * 64 + 2 * sp + 1];
        const float* pa = Vset + ((size_t)sa * NHEAD + h) * 64 + dd;
        const float* pb = Vset + ((size_t)sb * NHEAD + h) * 64 + dd;
        Vr[0] = *(const float4*)pa; Vr[1] = *(const float4*)(pa + 4);
        Vr[2] = *(const float4*)pb; Vr[3] = *(const float4*)(pb + 4);
    };
    auto prefK = [&](int tile) {
        int sK = sidAll[tile * 64 + wave * 16 + lane15];
        const float* kp = Kset + ((size_t)sK * NHEAD + h) * 64 + quad * 8;
        Kr[0] = *(const float4*)kp;        Kr[1] = *(const float4*)(kp + 4);
        Kr[2] = *(const float4*)(kp + 32); Kr[3] = *(const float4*)(kp + 36);
    };
    prefV(0); prefK(0);

    for (int tile = 0; tile < ntiles; ++tile) {
        __syncthreads();   // B1: prev tile's PV/rescale reads done

        // stage V^T bf16 pairs from prefetched regs
        {
            const float* va = (const float*)&Vr[0];   // dims dd..dd+7 of even set
            const float* vb = (const float*)&Vr[2];   // of odd set
            #pragma unroll
            for (int i = 0; i < 8; ++i)
                vP[dd + i][sp] = pack2_bf16_rne(va[i], vb[i]);
        }

        // K fragments: split prefetched regs
        short8 Khi[2], Klo[2];
        {
            float f[8];
            *(float4*)&f[0] = Kr[0]; *(float4*)&f[4] = Kr[1];
            split8_bf16(f, Khi[0], Klo[0]);
            *(float4*)&f[0] = Kr[2]; *(float4*)&f[4] = Kr[3];
            split8_bf16(f, Khi[1], Klo[1]);
        }

        // QK^T 3-term split
        f32x4 lacc[2];
        lacc[0] = (f32x4){0.f, 0.f, 0.f, 0.f};
        lacc[1] = (f32x4){0.f, 0.f, 0.f, 0.f};
        #pragma unroll
        for (int kt = 0; kt < 2; ++kt)
            #pragma unroll
            for (int ms = 0; ms < 2; ++ms) {
                lacc[ms] = __builtin_amdgcn_mfma_f32_16x16x32_bf16(Qhi[ms][kt], Khi[kt], lacc[ms], 0, 0, 0);
                lacc[ms] = __builtin_amdgcn_mfma_f32_16x16x32_bf16(Qlo[ms][kt], Khi[kt], lacc[ms], 0, 0, 0);
                lacc[ms] = __builtin_amdgcn_mfma_f32_16x16x32_bf16(Qhi[ms][kt], Klo[kt], lacc[ms], 0, 0, 0);
            }

        // mask + scale -> sS
        {
            const int sendv = sendAll[tile * 64 + wave * 16 + lane15];
            #pragma unroll
            for (int ms = 0; ms < 2; ++ms)
                #pragma unroll
                for (int r = 0; r < 4; ++r) {
                    int qrow = ms * 16 + quad * 4 + r;
                    bool ok = (T0 + qrow + 1) >= sendv;
                    sS[qrow][wave * 16 + lane15] = ok ? lacc[ms][r] * 0.125f : -1e30f;
                }
        }

        // issue prefetch for next tile (latency overlaps softmax)
        if (tile + 1 < ntiles) { prefV(tile + 1); prefK(tile + 1); }

        __syncthreads();   // B2: sS + vP visible

        // register softmax: thread owns row, cols part*8..+7
        {
            float4 a = *(float4*)&sS[row][part * 8];
            float4 c4 = *(float4*)&sS[row][part * 8 + 4];
            float mx = fmaxf(fmaxf(fmaxf(a.x, a.y), fmaxf(a.z, a.w)),
                             fmaxf(fmaxf(c4.x, c4.y), fmaxf(c4.z, c4.w)));
            mx = fmaxf(mx, __shfl_xor(mx, 1));
            mx = fmaxf(mx, __shfl_xor(mx, 2));
            mx = fmaxf(mx, __shfl_xor(mx, 4));
            float mnew = fmaxf(mreg, mx);
            float al = __expf(mreg - mnew);
            mreg = mnew;
            a.x = a.x > -1e29f ? __expf(a.x - mnew) : 0.f;
            a.y = a.y > -1e29f ? __expf(a.y - mnew) : 0.f;
            a.z = a.z > -1e29f ? __expf(a.z - mnew) : 0.f;
            a.w = a.w > -1e29f ? __expf(a.w - mnew) : 0.f;
            c4.x = c4.x > -1e29f ? __expf(c4.x - mnew) : 0.f;
            c4.y = c4.y > -1e29f ? __expf(c4.y - mnew) : 0.f;
            c4.z = c4.z > -1e29f ? __expf(c4.z - mnew) : 0.f;
            c4.w = c4.w > -1e29f ? __expf(c4.w - mnew) : 0.f;
            float sm = (a.x + a.y + a.z + a.w) + (c4.x + c4.y + c4.z + c4.w);
            sm += __shfl_xor(sm, 1);
            sm += __shfl_xor(sm, 2);
            sm += __shfl_xor(sm, 4);
            lreg = al * lreg + sm;
            // pack P -> bf16 pairs (k, k+1)
            unsigned w0 = pack2_bf16_rne(a.x, a.y);
            unsigned w1 = pack2_bf16_rne(a.z, a.w);
            unsigned w2 = pack2_bf16_rne(c4.x, c4.y);
            unsigned w3 = pack2_bf16_rne(c4.z, c4.w);
            *(uint4*)&sP[row][part * 4] = make_uint4(w0, w1, w2, w3);
            if (part == 0) arowS[row] = al;
        }

        __syncthreads();   // B3: sP + arowS visible

        // rescale + PV
        #pragma unroll
        for (int ms = 0; ms < 2; ++ms)
            #pragma unroll
            for (int r = 0; r < 4; ++r)
                oacc[ms][r] *= arowS[ms * 16 + quad * 4 + r];

        #pragma unroll
        for (int kt = 0; kt < 2; ++kt) {
            short8 Vf = *(short8*)&vP[wave * 16 + lane15][kt * 16 + quad * 4];
            #pragma unroll
            for (int ms = 0; ms < 2; ++ms) {
                short8 Pf = *(short8*)&sP[ms * 16 + lane15][kt * 16 + quad * 4];
                oacc[ms] = __builtin_amdgcn_mfma_f32_16x16x32_bf16(Pf, Vf, oacc[ms], 0, 0, 0);
            }
        }
    }

    // tail column (register state)
    {
        const float* qr = qbuf  + ((size_t)(T0 + row) * NHEAD + h) * 64 + part * 8;
        const float* kr = Ktail + ((size_t)(T0 + row) * NHEAD + h) * 64 + part * 8;
        float4 qa = *(const float4*)qr, qb = *(const float4*)(qr + 4);
        float4 ka = *(const float4*)kr, kb = *(const float4*)(kr + 4);
        float dp = qa.x * ka.x + qa.y * ka.y + qa.z * ka.z + qa.w * ka.w
                 + qb.x * kb.x + qb.y * kb.y + qb.z * kb.z + qb.w * kb.w;
        dp += __shfl_xor(dp, 1);
        dp += __shfl_xor(dp, 2);
        dp += __shfl_xor(dp, 4);
        float tl = dp * 0.125f;
        float mf = fmaxf(mreg, tl);
        float al = __expf(mreg - mf);
        float pt = __expf(tl - mf);
        float lf = al * lreg + pt;
        float inv = 1.f / lf;
        if (part == 0) { alS[row] = al * inv; ptS[row] = pt * inv; }
    }
    __syncthreads();

    #pragma unroll
    for (int ms = 0; ms < 2; ++ms)
        #pragma unroll
        for (int r = 0; r < 4; ++r) {
            int qrow = ms * 16 + quad * 4 + r;
            int col = wave * 16 + lane15;
            float al_inv = alS[qrow];
            float ptinv = ptS[qrow];
            size_t base = ((size_t)(T0 + qrow) * NHEAD + h) * 64 + col;
            attout[base] = oacc[ms][r] * al_inv + ptinv * Vtail[base];
        }
}

extern "C" void kernel_launch(void* const* d_in, const int* in_sizes, int n_in,
                              void* d_out, int out_size, void* d_ws, size_t ws_size,
                              hipStream_t stream)
{
    const float* x   = (const float*)d_in[0];
    const float* Wq  = (const float*)d_in[1];
    const float* Wk  = (const float*)d_in[2];
    const float* Wv  = (const float*)d_in[3];
    const float* Wks = (const float*)d_in[4];
    const float* bks = (const float*)d_in[5];
    const float* Wvs = (const float*)d_in[6];
    const float* bvs = (const float*)d_in[7];
    const float* Wc  = (const float*)d_in[8];
    const float* bc  = (const float*)d_in[9];
    float* out = (float*)d_out;

    float* ws = (float*)d_ws;
    const size_t TC = (size_t)TLEN * CDIM;
    float* q      = ws;
    float* k      = q + TC;
    float* v      = k + TC;
    float* kkv    = v + TC;
    float* vvv    = kkv + TC;
    float* Kt     = vvv + TC;
    float* Vt     = Kt + TC;
    float* Kset   = Vt + TC;
    float* Vset   = Kset + (size_t)NSETS * CDIM;
    float* attout = Vset + (size_t)NSETS * CDIM;
    _Float16* WblobMap = (_Float16*)attout;
    _Float16* blobQKV  = (_Float16*)(attout + 262144);
    float* scrK = attout + 1146880;
    float* scrV = scrK + 12 * 16 * 64;
    _Float16* blobC = (_Float16*)k;   // k dead after map_f16

    prep_w768x3<<<3 * 2304, 256, 0, stream>>>(Wq, Wk, Wv, blobQKV);
    prep_w<<<(4096 * 128) / 256, 256, 0, stream>>>(Wks, Wvs, WblobMap);

    gemm_qkv<<<dim3(36, 64), 256, 0, stream>>>(x, blobQKV, q);

    map_f16<<<(TLEN * NHEAD) / 32, 256, 0, stream>>>(k, v, WblobMap, kkv, vvv);

    prep_w768<<<2304, 256, 0, stream>>>(Wc, blobC);

    set_lower<<<16 * NHEAD, 256, 0, stream>>>(kkv, vvv, bks, bvs, Kset, Vset, scrK, scrV, Kt, Vt);
    set_upper<<<NHEAD, 256, 0, stream>>>(scrK, scrV, bks, bvs, Kset, Vset);

    attn_mfma<<<(TLEN / 32) * NHEAD, 256, 0, stream>>>(q, Kset, Vset, Kt, Vt, attout);

    gemm_mfma<0, 1><<<dim3(12, 64), 256, 0, stream>>>(attout, blobC, bc, out, TLEN, CDIM, CDIM);
}